// Round 1
// baseline (5967.496 us; speedup 1.0000x reference)
//
#include <hip/hip_runtime.h>
#include <math.h>

#define NNODES 10000
#define NEDGES 160000
#define ETOT   (NEDGES + NNODES)   // 170000, with self loops
#define NGRAPH 64
#define LN_EPS 1e-5f
#define NEG_SLOPE 0.2f

// ---------- helpers: order-preserving float<->uint map for atomicMax ----------
__device__ __forceinline__ unsigned fmap(float f) {
    unsigned u = __float_as_uint(f);
    return (u & 0x80000000u) ? ~u : (u | 0x80000000u);
}
__device__ __forceinline__ float funmap(unsigned m) {
    return (m & 0x80000000u) ? __uint_as_float(m & 0x7fffffffu) : __uint_as_float(~m);
}

// ---------- fp32 tiled GEMM:  C[M,N] = A[M,K] @ B[K,N] + bias[N] ----------
// 64x64 tile, 256 threads, 4x4 per thread, K-tile 16.
__global__ __launch_bounds__(256) void gemm_bias(
    const float* __restrict__ A, const float* __restrict__ B,
    const float* __restrict__ bias, float* __restrict__ C,
    int M, int K, int N)
{
    __shared__ float As[16][68];
    __shared__ float Bs[16][68];
    const int tid = threadIdx.x;
    const int col0 = blockIdx.x * 64;
    const int row0 = blockIdx.y * 64;
    const int tx = tid & 15, ty = tid >> 4;

    const int a_k = tid & 15, a_r = tid >> 4;   // A tile: 16 k x 64 rows
    const int b_c = tid & 63, b_k = tid >> 6;   // B tile: 16 k x 64 cols

    float acc[4][4] = {};

    for (int k0 = 0; k0 < K; k0 += 16) {
#pragma unroll
        for (int i = 0; i < 4; i++) {
            int r = a_r + i * 16;
            int gr = row0 + r, gk = k0 + a_k;
            As[a_k][r] = (gr < M && gk < K) ? A[(long)gr * K + gk] : 0.f;
        }
#pragma unroll
        for (int i = 0; i < 4; i++) {
            int kk = b_k + i * 4;
            int gk = k0 + kk, gc = col0 + b_c;
            Bs[kk][b_c] = (gk < K && gc < N) ? B[(long)gk * N + gc] : 0.f;
        }
        __syncthreads();
#pragma unroll
        for (int kk = 0; kk < 16; kk++) {
            float ra[4], rb[4];
#pragma unroll
            for (int i = 0; i < 4; i++) ra[i] = As[kk][ty * 4 + i];
#pragma unroll
            for (int j = 0; j < 4; j++) rb[j] = Bs[kk][tx * 4 + j];
#pragma unroll
            for (int i = 0; i < 4; i++)
#pragma unroll
                for (int j = 0; j < 4; j++) acc[i][j] += ra[i] * rb[j];
        }
        __syncthreads();
    }
#pragma unroll
    for (int i = 0; i < 4; i++) {
        int r = row0 + ty * 4 + i;
        if (r >= M) continue;
#pragma unroll
        for (int j = 0; j < 4; j++) {
            int c = col0 + tx * 4 + j;
            if (c < N) C[(long)r * N + c] = acc[i][j] + bias[c];
        }
    }
}

// ---------- edge logits: one wave (64 lanes) per edge ----------
// logit[e,h] = sum_c att[h,c] * leaky_relu(xl[src][h,c] + xr[dst][h,c])
// also atomicMax into per-(dst,head) running max (mapped uints, init 0 == -inf)
template<int HC, int H>
__global__ __launch_bounds__(256) void edge_logits(
    const float* __restrict__ xl, const float* __restrict__ xr,
    const int* __restrict__ ei, const float* __restrict__ att,
    float* __restrict__ logit, unsigned* __restrict__ mbuf)
{
    constexpr int C = HC / H;
    constexpr int P = HC / 64;       // elements per lane (8 or 2)
    constexpr int GRP = C / P;       // lanes per head (16 or 64)
    int widx = (blockIdx.x * blockDim.x + threadIdx.x) >> 6;
    int lane = threadIdx.x & 63;
    if (widx >= ETOT) return;
    int s, d;
    if (widx < NEDGES) { s = ei[widx]; d = ei[NEDGES + widx]; }
    else { s = widx - NEDGES; d = s; }

    const float* pl = xl + (long)s * HC;
    const float* pr = xr + (long)d * HC;
    int base = lane * P;

    float a[P], b[P], w[P];
    if constexpr (P == 8) {
        *(float4*)(a)     = *(const float4*)(pl + base);
        *(float4*)(a + 4) = *(const float4*)(pl + base + 4);
        *(float4*)(b)     = *(const float4*)(pr + base);
        *(float4*)(b + 4) = *(const float4*)(pr + base + 4);
        *(float4*)(w)     = *(const float4*)(att + base);
        *(float4*)(w + 4) = *(const float4*)(att + base + 4);
    } else {
        *(float2*)(a) = *(const float2*)(pl + base);
        *(float2*)(b) = *(const float2*)(pr + base);
        *(float2*)(w) = *(const float2*)(att + base);
    }
    float part = 0.f;
#pragma unroll
    for (int j = 0; j < P; j++) {
        float v = a[j] + b[j];
        v = v > 0.f ? v : v * NEG_SLOPE;
        part += v * w[j];
    }
#pragma unroll
    for (int off = GRP / 2; off > 0; off >>= 1) part += __shfl_xor(part, off);

    if ((lane % GRP) == 0) {
        int h = base / C;
        logit[(long)widx * H + h] = part;
        atomicMax(&mbuf[(long)d * H + h], fmap(part));
    }
}

// ---------- p = exp(logit - m[dst]), atomicAdd into denom[dst] ----------
template<int H>
__global__ __launch_bounds__(256) void edge_p(
    const int* __restrict__ ei, float* __restrict__ logit,
    const unsigned* __restrict__ mbuf, float* __restrict__ denom)
{
    int idx = blockIdx.x * blockDim.x + threadIdx.x;
    if (idx >= ETOT * H) return;
    int e = idx / H, h = idx - e * H;
    int d = (e < NEDGES) ? ei[NEDGES + e] : e - NEDGES;
    float m = funmap(mbuf[d * H + h]);
    float p = __expf(logit[idx] - m);
    logit[idx] = p;
    atomicAdd(&denom[d * H + h], p);
}

// ---------- aggregate: out[dst] += (p/denom) * xl[src], wave per edge ----------
template<int HC, int H>
__global__ __launch_bounds__(256) void edge_agg(
    const float* __restrict__ xl, const int* __restrict__ ei,
    const float* __restrict__ p, const float* __restrict__ denom,
    float* __restrict__ out)
{
    constexpr int C = HC / H;
    constexpr int P = HC / 64;
    int widx = (blockIdx.x * blockDim.x + threadIdx.x) >> 6;
    int lane = threadIdx.x & 63;
    if (widx >= ETOT) return;
    int s, d;
    if (widx < NEDGES) { s = ei[widx]; d = ei[NEDGES + widx]; }
    else { s = widx - NEDGES; d = s; }

    int base = lane * P;
    int h = base / C;
    float alpha = p[(long)widx * H + h] / denom[(long)d * H + h];

    const float* pl = xl + (long)s * HC;
    float* po = out + (long)d * HC;
    float a[P];
    if constexpr (P == 8) {
        *(float4*)(a)     = *(const float4*)(pl + base);
        *(float4*)(a + 4) = *(const float4*)(pl + base + 4);
    } else {
        *(float2*)(a) = *(const float2*)(pl + base);
    }
#pragma unroll
    for (int j = 0; j < P; j++) atomicAdd(&po[base + j], alpha * a[j]);
}

// ---------- epilogue: +bo, LayerNorm, ELU; block (128 thr) per node ----------
template<int HC>
__global__ __launch_bounds__(128) void ln_elu(
    const float* __restrict__ hin, const float* __restrict__ bo,
    const float* __restrict__ gam, const float* __restrict__ bet,
    float* __restrict__ xout)
{
    constexpr int T = 128, P = HC / T;
    int node = blockIdx.x, tid = threadIdx.x;
    const float* ph = hin + (long)node * HC;
    float v[P];
    float s = 0.f;
#pragma unroll
    for (int j = 0; j < P; j++) {
        int idx = tid + j * T;
        v[j] = ph[idx] + bo[idx];
        s += v[j];
    }
    __shared__ float red[2], red2[2];
#pragma unroll
    for (int off = 32; off > 0; off >>= 1) s += __shfl_xor(s, off);
    if ((tid & 63) == 0) red[tid >> 6] = s;
    __syncthreads();
    float mu = (red[0] + red[1]) / (float)HC;
    float q = 0.f;
#pragma unroll
    for (int j = 0; j < P; j++) { float dd = v[j] - mu; q += dd * dd; }
#pragma unroll
    for (int off = 32; off > 0; off >>= 1) q += __shfl_xor(q, off);
    if ((tid & 63) == 0) red2[tid >> 6] = q;
    __syncthreads();
    float rstd = rsqrtf((red2[0] + red2[1]) / (float)HC + LN_EPS);
#pragma unroll
    for (int j = 0; j < P; j++) {
        int idx = tid + j * T;
        float y = (v[j] - mu) * rstd * gam[idx] + bet[idx];
        xout[(long)node * HC + idx] = y > 0.f ? y : expm1f(y);
    }
}

// ---------- global mean pool (atomic accumulate) ----------
__global__ __launch_bounds__(256) void pool_kernel(
    const float* __restrict__ x, const int* __restrict__ batch,
    float* __restrict__ sums, int* __restrict__ cnt)
{
    int idx = blockIdx.x * blockDim.x + threadIdx.x;
    if (idx >= NNODES * 128) return;
    int n = idx >> 7, c = idx & 127;
    int b = batch[n];
    atomicAdd(&sums[b * 128 + c], x[idx]);
    if (c == 0) atomicAdd(&cnt[b], 1);
}

// ---------- MLP head: one block (128 thr) per graph ----------
__global__ __launch_bounds__(128) void mlp_kernel(
    const float* __restrict__ sums, const int* __restrict__ cnt,
    const float* __restrict__ W1, const float* __restrict__ b1,
    const float* __restrict__ W2, const float* __restrict__ b2,
    const float* __restrict__ W3, const float* __restrict__ b3,
    float* __restrict__ out)
{
    __shared__ float pool[128], h1[128], h2[64];
    int g = blockIdx.x, t = threadIdx.x;
    float c = (float)max(cnt[g], 1);
    pool[t] = sums[g * 128 + t] / c;
    __syncthreads();
    float a = b1[t];
    for (int k = 0; k < 128; k++) a += pool[k] * W1[k * 128 + t];
    h1[t] = fmaxf(a, 0.f);
    __syncthreads();
    if (t < 64) {
        float a2 = b2[t];
        for (int k = 0; k < 128; k++) a2 += h1[k] * W2[k * 64 + t];
        h2[t] = fmaxf(a2, 0.f);
    }
    __syncthreads();
    if (t == 0) {
        float a3 = b3[0];
        for (int k = 0; k < 64; k++) a3 += h2[k] * W3[k];
        out[g] = a3;
    }
}

// =====================================================================
extern "C" void kernel_launch(void* const* d_in, const int* in_sizes, int n_in,
                              void* d_out, int out_size, void* d_ws, size_t ws_size,
                              hipStream_t stream)
{
    const float* x     = (const float*)d_in[0];
    const int*   ei    = (const int*)d_in[1];
    const int*   batch = (const int*)d_in[2];

    const float *Wl[3], *bl[3], *Wr[3], *br[3], *att[3], *bo[3], *ga[3], *be[3];
    for (int l = 0; l < 3; l++) {
        int o = 3 + l * 8;
        Wl[l]  = (const float*)d_in[o + 0];
        bl[l]  = (const float*)d_in[o + 1];
        Wr[l]  = (const float*)d_in[o + 2];
        br[l]  = (const float*)d_in[o + 3];
        att[l] = (const float*)d_in[o + 4];
        bo[l]  = (const float*)d_in[o + 5];
        ga[l]  = (const float*)d_in[o + 6];
        be[l]  = (const float*)d_in[o + 7];
    }
    const float* W1 = (const float*)d_in[27];
    const float* b1 = (const float*)d_in[28];
    const float* W2 = (const float*)d_in[29];
    const float* b2 = (const float*)d_in[30];
    const float* W3 = (const float*)d_in[31];
    const float* b3 = (const float*)d_in[32];

    // workspace layout (256B aligned slices)
    char* w = (char*)d_ws;
    size_t off = 0;
    auto alloc = [&](size_t bytes) {
        void* p = w + off;
        off += (bytes + 255) & ~(size_t)255;
        return p;
    };
    float*    xl    = (float*)alloc((size_t)NNODES * 512 * 4);
    float*    xr    = (float*)alloc((size_t)NNODES * 512 * 4);
    float*    hbuf  = (float*)alloc((size_t)NNODES * 512 * 4);
    float*    xnext = (float*)alloc((size_t)NNODES * 512 * 4);
    float*    pbuf  = (float*)alloc((size_t)ETOT * 4 * 4);
    unsigned* mbuf  = (unsigned*)alloc((size_t)NNODES * 4 * 4);
    float*    denom = (float*)alloc((size_t)NNODES * 4 * 4);
    float*    psum  = (float*)alloc((size_t)NGRAPH * 128 * 4);
    int*      pcnt  = (int*)alloc((size_t)NGRAPH * 4);

    const int edge_waves_grid = (ETOT * 64 + 255) / 256;

    const float* xin = x;
    int Din = 771;
    for (int l = 0; l < 3; l++) {
        const int H  = (l < 2) ? 4 : 1;
        const int HC = (l < 2) ? 512 : 128;

        dim3 ggrid(HC / 64, (NNODES + 63) / 64);
        gemm_bias<<<ggrid, 256, 0, stream>>>(xin, Wl[l], bl[l], xl, NNODES, Din, HC);
        gemm_bias<<<ggrid, 256, 0, stream>>>(xin, Wr[l], br[l], xr, NNODES, Din, HC);

        hipMemsetAsync(mbuf, 0, (size_t)NNODES * H * 4, stream);
        hipMemsetAsync(denom, 0, (size_t)NNODES * H * 4, stream);
        hipMemsetAsync(hbuf, 0, (size_t)NNODES * HC * 4, stream);

        if (l < 2) {
            edge_logits<512, 4><<<edge_waves_grid, 256, 0, stream>>>(xl, xr, ei, att[l], pbuf, mbuf);
            edge_p<4><<<(ETOT * 4 + 255) / 256, 256, 0, stream>>>(ei, pbuf, mbuf, denom);
            edge_agg<512, 4><<<edge_waves_grid, 256, 0, stream>>>(xl, ei, pbuf, denom, hbuf);
            ln_elu<512><<<NNODES, 128, 0, stream>>>(hbuf, bo[l], ga[l], be[l], xnext);
        } else {
            edge_logits<128, 1><<<edge_waves_grid, 256, 0, stream>>>(xl, xr, ei, att[l], pbuf, mbuf);
            edge_p<1><<<(ETOT + 255) / 256, 256, 0, stream>>>(ei, pbuf, mbuf, denom);
            edge_agg<128, 1><<<edge_waves_grid, 256, 0, stream>>>(xl, ei, pbuf, denom, hbuf);
            ln_elu<128><<<NNODES, 128, 0, stream>>>(hbuf, bo[l], ga[l], be[l], xnext);
        }
        xin = xnext;
        Din = HC;
    }

    hipMemsetAsync(psum, 0, (size_t)NGRAPH * 128 * 4, stream);
    hipMemsetAsync(pcnt, 0, (size_t)NGRAPH * 4, stream);
    pool_kernel<<<(NNODES * 128 + 255) / 256, 256, 0, stream>>>(xnext, batch, psum, pcnt);
    mlp_kernel<<<NGRAPH, 128, 0, stream>>>(psum, pcnt, W1, b1, W2, b2, W3, b3, (float*)d_out);
}

// Round 2
// 1066.669 us; speedup vs baseline: 5.5945x; 5.5945x over previous
//
#include <hip/hip_runtime.h>
#include <math.h>

#define NNODES 10000
#define NEDGES 160000
#define ETOT   (NEDGES + NNODES)   // 170000, with self loops
#define NGRAPH 64
#define LN_EPS 1e-5f
#define NEG_SLOPE 0.2f

// ---------- fp32 tiled GEMM:  C[M,N] = A[M,K] @ B[K,N] + bias[N] ----------
__global__ __launch_bounds__(256) void gemm_bias(
    const float* __restrict__ A, const float* __restrict__ B,
    const float* __restrict__ bias, float* __restrict__ C,
    int M, int K, int N)
{
    __shared__ float As[16][68];
    __shared__ float Bs[16][68];
    const int tid = threadIdx.x;
    const int col0 = blockIdx.x * 64;
    const int row0 = blockIdx.y * 64;
    const int tx = tid & 15, ty = tid >> 4;

    const int a_k = tid & 15, a_r = tid >> 4;   // A tile: 16 k x 64 rows
    const int b_c = tid & 63, b_k = tid >> 6;   // B tile: 16 k x 64 cols

    float acc[4][4] = {};

    for (int k0 = 0; k0 < K; k0 += 16) {
#pragma unroll
        for (int i = 0; i < 4; i++) {
            int r = a_r + i * 16;
            int gr = row0 + r, gk = k0 + a_k;
            As[a_k][r] = (gr < M && gk < K) ? A[(long)gr * K + gk] : 0.f;
        }
#pragma unroll
        for (int i = 0; i < 4; i++) {
            int kk = b_k + i * 4;
            int gk = k0 + kk, gc = col0 + b_c;
            Bs[kk][b_c] = (gk < K && gc < N) ? B[(long)gk * N + gc] : 0.f;
        }
        __syncthreads();
#pragma unroll
        for (int kk = 0; kk < 16; kk++) {
            float ra[4], rb[4];
#pragma unroll
            for (int i = 0; i < 4; i++) ra[i] = As[kk][ty * 4 + i];
#pragma unroll
            for (int j = 0; j < 4; j++) rb[j] = Bs[kk][tx * 4 + j];
#pragma unroll
            for (int i = 0; i < 4; i++)
#pragma unroll
                for (int j = 0; j < 4; j++) acc[i][j] += ra[i] * rb[j];
        }
        __syncthreads();
    }
#pragma unroll
    for (int i = 0; i < 4; i++) {
        int r = row0 + ty * 4 + i;
        if (r >= M) continue;
#pragma unroll
        for (int j = 0; j < 4; j++) {
            int c = col0 + tx * 4 + j;
            if (c < N) C[(long)r * N + c] = acc[i][j] + bias[c];
        }
    }
}

// ---------- CSR build: histogram ----------
__global__ __launch_bounds__(256) void hist_kernel(
    const int* __restrict__ ei, int* __restrict__ deg)
{
    int e = blockIdx.x * blockDim.x + threadIdx.x;
    if (e >= ETOT) return;
    int d = (e < NEDGES) ? ei[NEDGES + e] : e - NEDGES;
    atomicAdd(&deg[d], 1);
}

// ---------- CSR build: single-block exclusive scan over deg[NNODES] ----------
__global__ __launch_bounds__(256) void scan_kernel(
    const int* __restrict__ deg, int* __restrict__ rowptr)
{
    __shared__ int partial[256];
    const int t = threadIdx.x;
    const int CH = (NNODES + 255) / 256;      // 40
    const int lo = t * CH, hi = min(lo + CH, NNODES);
    int s = 0;
    for (int i = lo; i < hi; i++) s += deg[i];
    partial[t] = s;
    __syncthreads();
    // Hillis-Steele inclusive scan
    for (int off = 1; off < 256; off <<= 1) {
        int v = (t >= off) ? partial[t - off] : 0;
        __syncthreads();
        partial[t] += v;
        __syncthreads();
    }
    int run = partial[t] - s;                 // exclusive prefix for this chunk
    for (int i = lo; i < hi; i++) { rowptr[i] = run; run += deg[i]; }
    if (t == 255) rowptr[NNODES] = partial[255];
}

// ---------- CSR build: scatter src ids into dst-sorted order ----------
__global__ __launch_bounds__(256) void scatter_kernel(
    const int* __restrict__ ei, const int* __restrict__ rowptr,
    int* __restrict__ cursor, int* __restrict__ perm_src)
{
    int e = blockIdx.x * blockDim.x + threadIdx.x;
    if (e >= ETOT) return;
    int s, d;
    if (e < NEDGES) { s = ei[e]; d = ei[NEDGES + e]; }
    else { s = e - NEDGES; d = s; }
    int pos = atomicAdd(&cursor[d], 1);
    perm_src[rowptr[d] + pos] = s;
}

// ---------- fused GATv2 edge phase: one wave per dst node ----------
// online-softmax over incoming edges; no atomics, single xl gather per edge.
// out[node, base..base+P) = sum_e alpha_e * xl[src_e, base..base+P)
template<int HC, int H>
__global__ __launch_bounds__(256) void gat_fused(
    const float* __restrict__ xl, const float* __restrict__ xr,
    const float* __restrict__ att,
    const int* __restrict__ rowptr, const int* __restrict__ perm_src,
    float* __restrict__ out)
{
    constexpr int C = HC / H;
    constexpr int P = HC / 64;        // channels per lane: 8 (HC=512) or 2 (HC=128)
    constexpr int GRP = C / P;        // lanes per head group: 16 or 64
    const int lane = threadIdx.x & 63;
    const int wave = threadIdx.x >> 6;
    const int node = blockIdx.x * 4 + wave;
    if (node >= NNODES) return;

    const int base = lane * P;        // = h*C + (lane%GRP)*P

    float xrv[P], w[P];
    if constexpr (P == 8) {
        *(float4*)(xrv)     = *(const float4*)(xr + (long)node * HC + base);
        *(float4*)(xrv + 4) = *(const float4*)(xr + (long)node * HC + base + 4);
        *(float4*)(w)       = *(const float4*)(att + base);
        *(float4*)(w + 4)   = *(const float4*)(att + base + 4);
    } else {
        *(float2*)(xrv) = *(const float2*)(xr + (long)node * HC + base);
        *(float2*)(w)   = *(const float2*)(att + base);
    }

    float m = -1e30f, l = 0.f;
    float acc[P];
#pragma unroll
    for (int j = 0; j < P; j++) acc[j] = 0.f;

    const int r0 = rowptr[node], r1 = rowptr[node + 1];
    for (int k = r0; k < r1; k++) {
        const int s = perm_src[k];
        const float* pl = xl + (long)s * HC + base;
        float a[P];
        if constexpr (P == 8) {
            *(float4*)(a)     = *(const float4*)(pl);
            *(float4*)(a + 4) = *(const float4*)(pl + 4);
        } else {
            *(float2*)(a) = *(const float2*)(pl);
        }
        float part = 0.f;
#pragma unroll
        for (int j = 0; j < P; j++) {
            float v = a[j] + xrv[j];
            v = v > 0.f ? v : v * NEG_SLOPE;
            part += v * w[j];
        }
#pragma unroll
        for (int off = GRP / 2; off > 0; off >>= 1) part += __shfl_xor(part, off);
        // part = logit for this lane's head (uniform within the head group)
        float mn = fmaxf(m, part);
        float scale = __expf(m - mn);
        float pe = __expf(part - mn);
        l = l * scale + pe;
#pragma unroll
        for (int j = 0; j < P; j++) acc[j] = acc[j] * scale + pe * a[j];
        m = mn;
    }
    const float inv = 1.f / l;        // deg >= 1 (self loop), l > 0
    float* po = out + (long)node * HC + base;
    if constexpr (P == 8) {
        float4 o0 = { acc[0] * inv, acc[1] * inv, acc[2] * inv, acc[3] * inv };
        float4 o1 = { acc[4] * inv, acc[5] * inv, acc[6] * inv, acc[7] * inv };
        *(float4*)(po)     = o0;
        *(float4*)(po + 4) = o1;
    } else {
        float2 o0 = { acc[0] * inv, acc[1] * inv };
        *(float2*)(po) = o0;
    }
}

// ---------- epilogue: +bo, LayerNorm, ELU; block (128 thr) per node ----------
template<int HC>
__global__ __launch_bounds__(128) void ln_elu(
    const float* __restrict__ hin, const float* __restrict__ bo,
    const float* __restrict__ gam, const float* __restrict__ bet,
    float* __restrict__ xout)
{
    constexpr int T = 128, P = HC / T;
    int node = blockIdx.x, tid = threadIdx.x;
    const float* ph = hin + (long)node * HC;
    float v[P];
    float s = 0.f;
#pragma unroll
    for (int j = 0; j < P; j++) {
        int idx = tid + j * T;
        v[j] = ph[idx] + bo[idx];
        s += v[j];
    }
    __shared__ float red[2], red2[2];
#pragma unroll
    for (int off = 32; off > 0; off >>= 1) s += __shfl_xor(s, off);
    if ((tid & 63) == 0) red[tid >> 6] = s;
    __syncthreads();
    float mu = (red[0] + red[1]) / (float)HC;
    float q = 0.f;
#pragma unroll
    for (int j = 0; j < P; j++) { float dd = v[j] - mu; q += dd * dd; }
#pragma unroll
    for (int off = 32; off > 0; off >>= 1) q += __shfl_xor(q, off);
    if ((tid & 63) == 0) red2[tid >> 6] = q;
    __syncthreads();
    float rstd = rsqrtf((red2[0] + red2[1]) / (float)HC + LN_EPS);
#pragma unroll
    for (int j = 0; j < P; j++) {
        int idx = tid + j * T;
        float y = (v[j] - mu) * rstd * gam[idx] + bet[idx];
        xout[(long)node * HC + idx] = y > 0.f ? y : expm1f(y);
    }
}

// ---------- global mean pool (atomic accumulate) ----------
__global__ __launch_bounds__(256) void pool_kernel(
    const float* __restrict__ x, const int* __restrict__ batch,
    float* __restrict__ sums, int* __restrict__ cnt)
{
    int idx = blockIdx.x * blockDim.x + threadIdx.x;
    if (idx >= NNODES * 128) return;
    int n = idx >> 7, c = idx & 127;
    int b = batch[n];
    atomicAdd(&sums[b * 128 + c], x[idx]);
    if (c == 0) atomicAdd(&cnt[b], 1);
}

// ---------- MLP head: one block (128 thr) per graph ----------
__global__ __launch_bounds__(128) void mlp_kernel(
    const float* __restrict__ sums, const int* __restrict__ cnt,
    const float* __restrict__ W1, const float* __restrict__ b1,
    const float* __restrict__ W2, const float* __restrict__ b2,
    const float* __restrict__ W3, const float* __restrict__ b3,
    float* __restrict__ out)
{
    __shared__ float pool[128], h1[128], h2[64];
    int g = blockIdx.x, t = threadIdx.x;
    float c = (float)max(cnt[g], 1);
    pool[t] = sums[g * 128 + t] / c;
    __syncthreads();
    float a = b1[t];
    for (int k = 0; k < 128; k++) a += pool[k] * W1[k * 128 + t];
    h1[t] = fmaxf(a, 0.f);
    __syncthreads();
    if (t < 64) {
        float a2 = b2[t];
        for (int k = 0; k < 128; k++) a2 += h1[k] * W2[k * 64 + t];
        h2[t] = fmaxf(a2, 0.f);
    }
    __syncthreads();
    if (t == 0) {
        float a3 = b3[0];
        for (int k = 0; k < 64; k++) a3 += h2[k] * W3[k];
        out[g] = a3;
    }
}

// =====================================================================
extern "C" void kernel_launch(void* const* d_in, const int* in_sizes, int n_in,
                              void* d_out, int out_size, void* d_ws, size_t ws_size,
                              hipStream_t stream)
{
    const float* x     = (const float*)d_in[0];
    const int*   ei    = (const int*)d_in[1];
    const int*   batch = (const int*)d_in[2];

    const float *Wl[3], *bl[3], *Wr[3], *br[3], *att[3], *bo[3], *ga[3], *be[3];
    for (int l = 0; l < 3; l++) {
        int o = 3 + l * 8;
        Wl[l]  = (const float*)d_in[o + 0];
        bl[l]  = (const float*)d_in[o + 1];
        Wr[l]  = (const float*)d_in[o + 2];
        br[l]  = (const float*)d_in[o + 3];
        att[l] = (const float*)d_in[o + 4];
        bo[l]  = (const float*)d_in[o + 5];
        ga[l]  = (const float*)d_in[o + 6];
        be[l]  = (const float*)d_in[o + 7];
    }
    const float* W1 = (const float*)d_in[27];
    const float* b1 = (const float*)d_in[28];
    const float* W2 = (const float*)d_in[29];
    const float* b2 = (const float*)d_in[30];
    const float* W3 = (const float*)d_in[31];
    const float* b3 = (const float*)d_in[32];

    // workspace layout (256B aligned slices)
    char* w = (char*)d_ws;
    size_t off = 0;
    auto alloc = [&](size_t bytes) {
        void* p = w + off;
        off += (bytes + 255) & ~(size_t)255;
        return p;
    };
    float* xl       = (float*)alloc((size_t)NNODES * 512 * 4);
    float* xr       = (float*)alloc((size_t)NNODES * 512 * 4);
    float* hbuf     = (float*)alloc((size_t)NNODES * 512 * 4);
    float* xnext    = (float*)alloc((size_t)NNODES * 512 * 4);
    int*   deg      = (int*)alloc((size_t)NNODES * 4);
    int*   rowptr   = (int*)alloc((size_t)(NNODES + 1) * 4);
    int*   cursor   = (int*)alloc((size_t)NNODES * 4);
    int*   perm_src = (int*)alloc((size_t)ETOT * 4);
    float* psum     = (float*)alloc((size_t)NGRAPH * 128 * 4);
    int*   pcnt     = (int*)alloc((size_t)NGRAPH * 4);

    // ---- build CSR by destination (graph constant across layers) ----
    hipMemsetAsync(deg, 0, (size_t)NNODES * 4, stream);
    hipMemsetAsync(cursor, 0, (size_t)NNODES * 4, stream);
    hist_kernel<<<(ETOT + 255) / 256, 256, 0, stream>>>(ei, deg);
    scan_kernel<<<1, 256, 0, stream>>>(deg, rowptr);
    scatter_kernel<<<(ETOT + 255) / 256, 256, 0, stream>>>(ei, rowptr, cursor, perm_src);

    const float* xin = x;
    int Din = 771;
    for (int l = 0; l < 3; l++) {
        const int HC = (l < 2) ? 512 : 128;

        dim3 ggrid(HC / 64, (NNODES + 63) / 64);
        gemm_bias<<<ggrid, 256, 0, stream>>>(xin, Wl[l], bl[l], xl, NNODES, Din, HC);
        gemm_bias<<<ggrid, 256, 0, stream>>>(xin, Wr[l], br[l], xr, NNODES, Din, HC);

        const int fgrid = (NNODES + 3) / 4;   // one wave per node, 4 waves/block
        if (l < 2) {
            gat_fused<512, 4><<<fgrid, 256, 0, stream>>>(xl, xr, att[l], rowptr, perm_src, hbuf);
            ln_elu<512><<<NNODES, 128, 0, stream>>>(hbuf, bo[l], ga[l], be[l], xnext);
        } else {
            gat_fused<128, 1><<<fgrid, 256, 0, stream>>>(xl, xr, att[l], rowptr, perm_src, hbuf);
            ln_elu<128><<<NNODES, 128, 0, stream>>>(hbuf, bo[l], ga[l], be[l], xnext);
        }
        xin = xnext;
        Din = HC;
    }

    hipMemsetAsync(psum, 0, (size_t)NGRAPH * 128 * 4, stream);
    hipMemsetAsync(pcnt, 0, (size_t)NGRAPH * 4, stream);
    pool_kernel<<<(NNODES * 128 + 255) / 256, 256, 0, stream>>>(xnext, batch, psum, pcnt);
    mlp_kernel<<<NGRAPH, 128, 0, stream>>>(psum, pcnt, W1, b1, W2, b2, W3, b3, (float*)d_out);
}

// Round 3
// 580.635 us; speedup vs baseline: 10.2775x; 1.8371x over previous
//
#include <hip/hip_runtime.h>
#include <math.h>

#define NNODES 10000
#define MPAD   10112               // 79*128, padded row count for MFMA GEMM
#define NEDGES 160000
#define ETOT   (NEDGES + NNODES)   // 170000, with self loops
#define NGRAPH 64
#define LN_EPS 1e-5f
#define NEG_SLOPE 0.2f

typedef __bf16 bf16x8 __attribute__((ext_vector_type(8)));
typedef float  f32x4  __attribute__((ext_vector_type(4)));

// ---------- split a fp32 into hi/lo bf16 ----------
__device__ __forceinline__ void bf16_split(float v, __bf16& h, __bf16& l) {
    __bf16 bh = (__bf16)v;
    float  fh = (float)bh;
    h = bh;
    l = (__bf16)(v - fh);
}

// ---------- convert x [10000][771] fp32 -> Ah/Al [MPAD][800] bf16 (zero pad) ----------
__global__ __launch_bounds__(256) void convert_x(
    const float* __restrict__ x, __bf16* __restrict__ ah, __bf16* __restrict__ al)
{
    int idx = blockIdx.x * blockDim.x + threadIdx.x;
    if (idx >= MPAD * 800) return;
    int r = idx / 800, k = idx - r * 800;
    float v = (r < NNODES && k < 771) ? x[(size_t)r * 771 + k] : 0.f;
    __bf16 h, l;
    bf16_split(v, h, l);
    ah[idx] = h; al[idx] = l;
}

// ---------- pack weights: Wl|Wr [K][NW] -> Bh/Bl [Np][Kp] bf16 transposed, zero k-pad ----------
__global__ __launch_bounds__(256) void pack_w(
    const float* __restrict__ Wl, const float* __restrict__ Wr,
    const float* __restrict__ bl, const float* __restrict__ br,
    __bf16* __restrict__ bh, __bf16* __restrict__ blo, float* __restrict__ biasp,
    int K, int Kp, int NW, int Np)
{
    int idx = blockIdx.x * blockDim.x + threadIdx.x;
    if (idx < Np) biasp[idx] = (idx < NW) ? bl[idx] : br[idx - NW];
    if (idx >= Np * Kp) return;
    int n = idx / Kp, k = idx - n * Kp;
    float v = 0.f;
    if (k < K) v = (n < NW) ? Wl[(size_t)k * NW + n] : Wr[(size_t)k * NW + (n - NW)];
    __bf16 h, l;
    bf16_split(v, h, l);
    bh[idx] = h; blo[idx] = l;
}

// ---------- split-bf16 MFMA GEMM: C[M][N] = A[M][Kp] @ B[Kp][N] + bias ----------
// A (hi/lo): [MPAD][Kp] bf16 row-major (k contiguous). B (hi/lo): [N][Kp] bf16 (transposed).
// 128x128 tile, 256 threads (4 waves, each 64x64), BK=32, 16x16x32 bf16 MFMA.
// LDS: XOR-swizzled k-chunks so global_load_lds staging stays lane-linear.
__global__ __launch_bounds__(256) void gemm_mfma_split(
    const __bf16* __restrict__ Ah, const __bf16* __restrict__ Al,
    const __bf16* __restrict__ Bh, const __bf16* __restrict__ Bl,
    const float* __restrict__ bias, float* __restrict__ C,
    int M, int Kp, int N)
{
    __shared__ __align__(16) __bf16 sAh[128 * 32];
    __shared__ __align__(16) __bf16 sAl[128 * 32];
    __shared__ __align__(16) __bf16 sBh[128 * 32];
    __shared__ __align__(16) __bf16 sBl[128 * 32];

    const int tid  = threadIdx.x;
    const int lane = tid & 63;
    const int wave = tid >> 6;
    const int row0 = blockIdx.y * 128;
    const int col0 = blockIdx.x * 128;
    const int wr = (wave >> 1) * 64;  // wave's row quadrant
    const int wc = (wave & 1) * 64;   // wave's col quadrant
    const int fm = lane & 15;         // MFMA fragment row/col within 16
    const int fq = lane >> 4;         // MFMA k-quad

    f32x4 acc[4][4] = {};

    for (int k0 = 0; k0 < Kp; k0 += 32) {
#pragma unroll
        for (int it = 0; it < 2; ++it) {
            int chunk = tid + it * 256;          // 0..511, 16B chunks of the 8KB tile
            int r  = chunk >> 2;
            int kc = (chunk & 3) ^ (r & 3);      // XOR swizzle
            size_t ga = (size_t)(row0 + r) * Kp + k0 + kc * 8;
            size_t gb = (size_t)(col0 + r) * Kp + k0 + kc * 8;
            __builtin_amdgcn_global_load_lds(
                (const __attribute__((address_space(1))) void*)(Ah + ga),
                (__attribute__((address_space(3))) void*)(sAh + chunk * 8), 16, 0, 0);
            __builtin_amdgcn_global_load_lds(
                (const __attribute__((address_space(1))) void*)(Al + ga),
                (__attribute__((address_space(3))) void*)(sAl + chunk * 8), 16, 0, 0);
            __builtin_amdgcn_global_load_lds(
                (const __attribute__((address_space(1))) void*)(Bh + gb),
                (__attribute__((address_space(3))) void*)(sBh + chunk * 8), 16, 0, 0);
            __builtin_amdgcn_global_load_lds(
                (const __attribute__((address_space(1))) void*)(Bl + gb),
                (__attribute__((address_space(3))) void*)(sBl + chunk * 8), 16, 0, 0);
        }
        __syncthreads();

        bf16x8 fah[4], fal[4], fbh[4], fbl[4];
#pragma unroll
        for (int mi = 0; mi < 4; ++mi) {
            int m = wr + mi * 16 + fm;
            int off = (m * 4 + (fq ^ (m & 3))) * 8;     // swizzled chunk -> element offset
            fah[mi] = *(const bf16x8*)(sAh + off);
            fal[mi] = *(const bf16x8*)(sAl + off);
        }
#pragma unroll
        for (int ni = 0; ni < 4; ++ni) {
            int n = wc + ni * 16 + fm;
            int off = (n * 4 + (fq ^ (n & 3))) * 8;
            fbh[ni] = *(const bf16x8*)(sBh + off);
            fbl[ni] = *(const bf16x8*)(sBl + off);
        }
#pragma unroll
        for (int mi = 0; mi < 4; ++mi)
#pragma unroll
            for (int ni = 0; ni < 4; ++ni) {
                acc[mi][ni] = __builtin_amdgcn_mfma_f32_16x16x32_bf16(fah[mi], fbh[ni], acc[mi][ni], 0, 0, 0);
                acc[mi][ni] = __builtin_amdgcn_mfma_f32_16x16x32_bf16(fah[mi], fbl[ni], acc[mi][ni], 0, 0, 0);
                acc[mi][ni] = __builtin_amdgcn_mfma_f32_16x16x32_bf16(fal[mi], fbh[ni], acc[mi][ni], 0, 0, 0);
            }
        __syncthreads();
    }

    // epilogue: C/D layout col=lane&15, row=(lane>>4)*4+reg
    float bv[4];
#pragma unroll
    for (int ni = 0; ni < 4; ++ni) bv[ni] = bias[col0 + wc + ni * 16 + fm];
#pragma unroll
    for (int mi = 0; mi < 4; ++mi) {
        int grb = row0 + wr + mi * 16 + fq * 4;
#pragma unroll
        for (int reg = 0; reg < 4; ++reg) {
            int gr = grb + reg;
            if (gr < M) {
#pragma unroll
                for (int ni = 0; ni < 4; ++ni) {
                    int gc = col0 + wc + ni * 16 + fm;
                    C[(size_t)gr * N + gc] = acc[mi][ni][reg] + bv[ni];
                }
            }
        }
    }
}

// ---------- CSR build ----------
__global__ __launch_bounds__(256) void hist_kernel(
    const int* __restrict__ ei, int* __restrict__ deg)
{
    int e = blockIdx.x * blockDim.x + threadIdx.x;
    if (e >= ETOT) return;
    int d = (e < NEDGES) ? ei[NEDGES + e] : e - NEDGES;
    atomicAdd(&deg[d], 1);
}

__global__ __launch_bounds__(256) void scan_kernel(
    const int* __restrict__ deg, int* __restrict__ rowptr)
{
    __shared__ int partial[256];
    const int t = threadIdx.x;
    const int CH = (NNODES + 255) / 256;
    const int lo = t * CH, hi = min(lo + CH, NNODES);
    int s = 0;
    for (int i = lo; i < hi; i++) s += deg[i];
    partial[t] = s;
    __syncthreads();
    for (int off = 1; off < 256; off <<= 1) {
        int v = (t >= off) ? partial[t - off] : 0;
        __syncthreads();
        partial[t] += v;
        __syncthreads();
    }
    int run = partial[t] - s;
    for (int i = lo; i < hi; i++) { rowptr[i] = run; run += deg[i]; }
    if (t == 255) rowptr[NNODES] = partial[255];
}

__global__ __launch_bounds__(256) void scatter_kernel(
    const int* __restrict__ ei, const int* __restrict__ rowptr,
    int* __restrict__ cursor, int* __restrict__ perm_src)
{
    int e = blockIdx.x * blockDim.x + threadIdx.x;
    if (e >= ETOT) return;
    int s, d;
    if (e < NEDGES) { s = ei[e]; d = ei[NEDGES + e]; }
    else { s = e - NEDGES; d = s; }
    int pos = atomicAdd(&cursor[d], 1);
    perm_src[rowptr[d] + pos] = s;
}

// ---------- fused GATv2 edge phase: one wave per dst node, online softmax ----------
// cbuf holds xl|xr fused per row: xl at [node*ld], xr at [node*ld + HC].
template<int HC, int H>
__global__ __launch_bounds__(256) void gat_fused(
    const float* __restrict__ cbuf, const float* __restrict__ att,
    const int* __restrict__ rowptr, const int* __restrict__ perm_src,
    float* __restrict__ out, int ld)
{
    constexpr int C = HC / H;
    constexpr int P = HC / 64;
    constexpr int GRP = C / P;
    const int lane = threadIdx.x & 63;
    const int wave = threadIdx.x >> 6;
    const int node = blockIdx.x * 4 + wave;
    if (node >= NNODES) return;

    const int base = lane * P;

    float xrv[P], w[P];
    const float* pr = cbuf + (size_t)node * ld + HC + base;
    if constexpr (P == 8) {
        *(float4*)(xrv)     = *(const float4*)(pr);
        *(float4*)(xrv + 4) = *(const float4*)(pr + 4);
        *(float4*)(w)       = *(const float4*)(att + base);
        *(float4*)(w + 4)   = *(const float4*)(att + base + 4);
    } else {
        *(float2*)(xrv) = *(const float2*)(pr);
        *(float2*)(w)   = *(const float2*)(att + base);
    }

    float m = -1e30f, l = 0.f;
    float acc[P];
#pragma unroll
    for (int j = 0; j < P; j++) acc[j] = 0.f;

    const int r0 = rowptr[node], r1 = rowptr[node + 1];
    for (int k = r0; k < r1; k++) {
        const int s = perm_src[k];
        const float* pl = cbuf + (size_t)s * ld + base;
        float a[P];
        if constexpr (P == 8) {
            *(float4*)(a)     = *(const float4*)(pl);
            *(float4*)(a + 4) = *(const float4*)(pl + 4);
        } else {
            *(float2*)(a) = *(const float2*)(pl);
        }
        float part = 0.f;
#pragma unroll
        for (int j = 0; j < P; j++) {
            float v = a[j] + xrv[j];
            v = v > 0.f ? v : v * NEG_SLOPE;
            part += v * w[j];
        }
#pragma unroll
        for (int off = GRP / 2; off > 0; off >>= 1) part += __shfl_xor(part, off);
        float mn = fmaxf(m, part);
        float scale = __expf(m - mn);
        float pe = __expf(part - mn);
        l = l * scale + pe;
#pragma unroll
        for (int j = 0; j < P; j++) acc[j] = acc[j] * scale + pe * a[j];
        m = mn;
    }
    const float inv = 1.f / l;
    float* po = out + (size_t)node * HC + base;
    if constexpr (P == 8) {
        float4 o0 = { acc[0] * inv, acc[1] * inv, acc[2] * inv, acc[3] * inv };
        float4 o1 = { acc[4] * inv, acc[5] * inv, acc[6] * inv, acc[7] * inv };
        *(float4*)(po)     = o0;
        *(float4*)(po + 4) = o1;
    } else {
        float2 o0 = { acc[0] * inv, acc[1] * inv };
        *(float2*)(po) = o0;
    }
}

// ---------- epilogue: +bo, LayerNorm, ELU ----------
// EMIT=true: write bf16 hi/lo (next layer's GEMM A), zero-fill pad rows (grid=MPAD)
// EMIT=false: write fp32 xout (final layer, grid=NNODES)
template<int HC, bool EMIT>
__global__ __launch_bounds__(128) void ln_elu(
    const float* __restrict__ hin, const float* __restrict__ bo,
    const float* __restrict__ gam, const float* __restrict__ bet,
    float* __restrict__ xout, __bf16* __restrict__ ah, __bf16* __restrict__ al)
{
    constexpr int T = 128, P = HC / T;
    int node = blockIdx.x, tid = threadIdx.x;
    if (EMIT && node >= NNODES) {   // zero pad rows for the MFMA GEMM
#pragma unroll
        for (int j = 0; j < P; j++) {
            size_t idx = (size_t)node * HC + tid + j * T;
            ah[idx] = (__bf16)0.f; al[idx] = (__bf16)0.f;
        }
        return;
    }
    const float* ph = hin + (size_t)node * HC;
    float v[P];
    float s = 0.f;
#pragma unroll
    for (int j = 0; j < P; j++) {
        int idx = tid + j * T;
        v[j] = ph[idx] + bo[idx];
        s += v[j];
    }
    __shared__ float red[2], red2[2];
#pragma unroll
    for (int off = 32; off > 0; off >>= 1) s += __shfl_xor(s, off);
    if ((tid & 63) == 0) red[tid >> 6] = s;
    __syncthreads();
    float mu = (red[0] + red[1]) / (float)HC;
    float q = 0.f;
#pragma unroll
    for (int j = 0; j < P; j++) { float dd = v[j] - mu; q += dd * dd; }
#pragma unroll
    for (int off = 32; off > 0; off >>= 1) q += __shfl_xor(q, off);
    if ((tid & 63) == 0) red2[tid >> 6] = q;
    __syncthreads();
    float rstd = rsqrtf((red2[0] + red2[1]) / (float)HC + LN_EPS);
#pragma unroll
    for (int j = 0; j < P; j++) {
        int idx = tid + j * T;
        float y = (v[j] - mu) * rstd * gam[idx] + bet[idx];
        y = y > 0.f ? y : expm1f(y);
        if (EMIT) {
            __bf16 h, l;
            bf16_split(y, h, l);
            ah[(size_t)node * HC + idx] = h;
            al[(size_t)node * HC + idx] = l;
        } else {
            xout[(size_t)node * HC + idx] = y;
        }
    }
}

// ---------- global mean pool ----------
__global__ __launch_bounds__(256) void pool_kernel(
    const float* __restrict__ x, const int* __restrict__ batch,
    float* __restrict__ sums, int* __restrict__ cnt)
{
    int idx = blockIdx.x * blockDim.x + threadIdx.x;
    if (idx >= NNODES * 128) return;
    int n = idx >> 7, c = idx & 127;
    int b = batch[n];
    atomicAdd(&sums[b * 128 + c], x[idx]);
    if (c == 0) atomicAdd(&cnt[b], 1);
}

// ---------- MLP head ----------
__global__ __launch_bounds__(128) void mlp_kernel(
    const float* __restrict__ sums, const int* __restrict__ cnt,
    const float* __restrict__ W1, const float* __restrict__ b1,
    const float* __restrict__ W2, const float* __restrict__ b2,
    const float* __restrict__ W3, const float* __restrict__ b3,
    float* __restrict__ out)
{
    __shared__ float pool[128], h1[128], h2[64];
    int g = blockIdx.x, t = threadIdx.x;
    float c = (float)max(cnt[g], 1);
    pool[t] = sums[g * 128 + t] / c;
    __syncthreads();
    float a = b1[t];
    for (int k = 0; k < 128; k++) a += pool[k] * W1[k * 128 + t];
    h1[t] = fmaxf(a, 0.f);
    __syncthreads();
    if (t < 64) {
        float a2 = b2[t];
        for (int k = 0; k < 128; k++) a2 += h1[k] * W2[k * 64 + t];
        h2[t] = fmaxf(a2, 0.f);
    }
    __syncthreads();
    if (t == 0) {
        float a3 = b3[0];
        for (int k = 0; k < 64; k++) a3 += h2[k] * W3[k];
        out[g] = a3;
    }
}

// =====================================================================
extern "C" void kernel_launch(void* const* d_in, const int* in_sizes, int n_in,
                              void* d_out, int out_size, void* d_ws, size_t ws_size,
                              hipStream_t stream)
{
    const float* x     = (const float*)d_in[0];
    const int*   ei    = (const int*)d_in[1];
    const int*   batch = (const int*)d_in[2];

    const float *Wl[3], *bl[3], *Wr[3], *br[3], *att[3], *bo[3], *ga[3], *be[3];
    for (int l = 0; l < 3; l++) {
        int o = 3 + l * 8;
        Wl[l]  = (const float*)d_in[o + 0];
        bl[l]  = (const float*)d_in[o + 1];
        Wr[l]  = (const float*)d_in[o + 2];
        br[l]  = (const float*)d_in[o + 3];
        att[l] = (const float*)d_in[o + 4];
        bo[l]  = (const float*)d_in[o + 5];
        ga[l]  = (const float*)d_in[o + 6];
        be[l]  = (const float*)d_in[o + 7];
    }
    const float* W1 = (const float*)d_in[27];
    const float* b1 = (const float*)d_in[28];
    const float* W2 = (const float*)d_in[29];
    const float* b2 = (const float*)d_in[30];
    const float* W3 = (const float*)d_in[31];
    const float* b3 = (const float*)d_in[32];

    // workspace layout
    char* w = (char*)d_ws;
    size_t off = 0;
    auto alloc = [&](size_t bytes) {
        void* p = w + off;
        off += (bytes + 255) & ~(size_t)255;
        return p;
    };
    float*  cbuf  = (float*)alloc((size_t)NNODES * 1024 * 4);      // xl|xr fused GEMM out
    float*  hbuf  = (float*)alloc((size_t)NNODES * 512 * 4);       // gat output
    float*  xfin  = (float*)alloc((size_t)NNODES * 128 * 4);       // final layer fp32
    __bf16* Axh   = (__bf16*)alloc((size_t)MPAD * 800 * 2);        // layer0 A hi (also reused as A hi for layers 1/2, [MPAD][512])
    __bf16* Axl   = (__bf16*)alloc((size_t)MPAD * 800 * 2);
    __bf16* Bh0   = (__bf16*)alloc((size_t)1024 * 800 * 2);
    __bf16* Bl0   = (__bf16*)alloc((size_t)1024 * 800 * 2);
    __bf16* Bh1   = (__bf16*)alloc((size_t)1024 * 512 * 2);
    __bf16* Bl1   = (__bf16*)alloc((size_t)1024 * 512 * 2);
    __bf16* Bh2   = (__bf16*)alloc((size_t)256 * 512 * 2);
    __bf16* Bl2   = (__bf16*)alloc((size_t)256 * 512 * 2);
    float*  bp0   = (float*)alloc(1024 * 4);
    float*  bp1   = (float*)alloc(1024 * 4);
    float*  bp2   = (float*)alloc(256 * 4);
    int*    deg      = (int*)alloc((size_t)NNODES * 4);
    int*    rowptr   = (int*)alloc((size_t)(NNODES + 1) * 4);
    int*    cursor   = (int*)alloc((size_t)NNODES * 4);
    int*    perm_src = (int*)alloc((size_t)ETOT * 4);
    float*  psum     = (float*)alloc((size_t)NGRAPH * 128 * 4);
    int*    pcnt     = (int*)alloc((size_t)NGRAPH * 4);
    // A buffers for layers 1/2 alias the layer-0 x conversion buffers (dead after layer-0 GEMM)
    __bf16* Ah1 = Axh;   // [MPAD][512]
    __bf16* Al1 = Axl;

    // ---- input conversion + weight packing ----
    convert_x<<<(MPAD * 800 + 255) / 256, 256, 0, stream>>>(x, Axh, Axl);
    pack_w<<<(1024 * 800 + 255) / 256, 256, 0, stream>>>(Wl[0], Wr[0], bl[0], br[0], Bh0, Bl0, bp0, 771, 800, 512, 1024);
    pack_w<<<(1024 * 512 + 255) / 256, 256, 0, stream>>>(Wl[1], Wr[1], bl[1], br[1], Bh1, Bl1, bp1, 512, 512, 512, 1024);
    pack_w<<<(256 * 512 + 255) / 256, 256, 0, stream>>>(Wl[2], Wr[2], bl[2], br[2], Bh2, Bl2, bp2, 512, 512, 128, 256);

    // ---- build CSR by destination ----
    hipMemsetAsync(deg, 0, (size_t)NNODES * 4, stream);
    hipMemsetAsync(cursor, 0, (size_t)NNODES * 4, stream);
    hist_kernel<<<(ETOT + 255) / 256, 256, 0, stream>>>(ei, deg);
    scan_kernel<<<1, 256, 0, stream>>>(deg, rowptr);
    scatter_kernel<<<(ETOT + 255) / 256, 256, 0, stream>>>(ei, rowptr, cursor, perm_src);

    const int fgrid = (NNODES + 3) / 4;

    // ---- layer 0: [10000,771] x [771,1024] ----
    gemm_mfma_split<<<dim3(1024 / 128, MPAD / 128), 256, 0, stream>>>(
        Axh, Axl, Bh0, Bl0, bp0, cbuf, NNODES, 800, 1024);
    gat_fused<512, 4><<<fgrid, 256, 0, stream>>>(cbuf, att[0], rowptr, perm_src, hbuf, 1024);
    ln_elu<512, true><<<MPAD, 128, 0, stream>>>(hbuf, bo[0], ga[0], be[0], nullptr, Ah1, Al1);

    // ---- layer 1: [10000,512] x [512,1024] ----
    gemm_mfma_split<<<dim3(1024 / 128, MPAD / 128), 256, 0, stream>>>(
        Ah1, Al1, Bh1, Bl1, bp1, cbuf, NNODES, 512, 1024);
    gat_fused<512, 4><<<fgrid, 256, 0, stream>>>(cbuf, att[1], rowptr, perm_src, hbuf, 1024);
    ln_elu<512, true><<<MPAD, 128, 0, stream>>>(hbuf, bo[1], ga[1], be[1], nullptr, Ah1, Al1);

    // ---- layer 2: [10000,512] x [512,256] ----
    gemm_mfma_split<<<dim3(256 / 128, MPAD / 128), 256, 0, stream>>>(
        Ah1, Al1, Bh2, Bl2, bp2, cbuf, NNODES, 512, 256);
    gat_fused<128, 1><<<fgrid, 256, 0, stream>>>(cbuf, att[2], rowptr, perm_src, hbuf, 256);
    ln_elu<128, false><<<NNODES, 128, 0, stream>>>(hbuf, bo[2], ga[2], be[2], xfin, nullptr, nullptr);

    // ---- pool + MLP ----
    hipMemsetAsync(psum, 0, (size_t)NGRAPH * 128 * 4, stream);
    hipMemsetAsync(pcnt, 0, (size_t)NGRAPH * 4, stream);
    pool_kernel<<<(NNODES * 128 + 255) / 256, 256, 0, stream>>>(xfin, batch, psum, pcnt);
    mlp_kernel<<<NGRAPH, 128, 0, stream>>>(psum, pcnt, W1, b1, W2, b2, W3, b3, (float*)d_out);
}

// Round 4
// 520.260 us; speedup vs baseline: 11.4702x; 1.1160x over previous
//
#include <hip/hip_runtime.h>
#include <math.h>

#define NNODES 10000
#define MPAD   10240               // 80*128, padded row count for MFMA GEMM
#define NEDGES 160000
#define ETOT   (NEDGES + NNODES)   // 170000, with self loops
#define NGRAPH 64
#define LN_EPS 1e-5f
#define NEG_SLOPE 0.2f

typedef __bf16 bf16x8 __attribute__((ext_vector_type(8)));
typedef __bf16 bf16x2 __attribute__((ext_vector_type(2)));
typedef float  f32x4  __attribute__((ext_vector_type(4)));

// ---------- split a fp32 into hi/lo bf16 ----------
__device__ __forceinline__ void bf16_split(float v, __bf16& h, __bf16& l) {
    __bf16 bh = (__bf16)v;
    float  fh = (float)bh;
    h = bh;
    l = (__bf16)(v - fh);
}

// ---------- convert x [10000][771] fp32 -> Ah/Al [MPAD][800] bf16 (zero pad) ----------
__global__ __launch_bounds__(256) void convert_x(
    const float* __restrict__ x, __bf16* __restrict__ ah, __bf16* __restrict__ al)
{
    int idx = blockIdx.x * blockDim.x + threadIdx.x;
    if (idx >= MPAD * 800) return;
    int r = idx / 800, k = idx - r * 800;
    float v = (r < NNODES && k < 771) ? x[(size_t)r * 771 + k] : 0.f;
    __bf16 h, l;
    bf16_split(v, h, l);
    ah[idx] = h; al[idx] = l;
}

// ---------- pack weights: Wl|Wr [K][NW] -> Bh [Np][Kp] bf16 transposed (hi only) ----------
__global__ __launch_bounds__(256) void pack_w(
    const float* __restrict__ Wl, const float* __restrict__ Wr,
    const float* __restrict__ bl, const float* __restrict__ br,
    __bf16* __restrict__ bh, float* __restrict__ biasp,
    int K, int Kp, int NW, int Np)
{
    int idx = blockIdx.x * blockDim.x + threadIdx.x;
    if (idx < Np) biasp[idx] = (idx < NW) ? bl[idx] : br[idx - NW];
    if (idx >= Np * Kp) return;
    int n = idx / Kp, k = idx - n * Kp;
    float v = 0.f;
    if (k < K) v = (n < NW) ? Wl[(size_t)k * NW + n] : Wr[(size_t)k * NW + (n - NW)];
    bh[idx] = (__bf16)v;
}

// ---------- 2-term split MFMA GEMM: C = (Ah+Al) @ Bh + bias ----------
// A hi/lo [MPAD][Kp] bf16 row-major; B [N][Kp] bf16 (transposed). 128x128 tile,
// 4 waves x 64x64, BK=32, 16x16x32 MFMA, XOR-swizzled LDS.
// XCD-aware 1-D grid: xcd = L&7 owns row-tile stripe by = xcd+8*(t>>lognbx) for
// ALL col-tiles -> per-XCD L2 holds the whole B panel; A rows fetched ~once.
// Epilogue: cols < N/2 are xl -> bf16; cols >= N/2 are xr -> fp32.
__global__ __launch_bounds__(256) void gemm_mfma(
    const __bf16* __restrict__ Ah, const __bf16* __restrict__ Al,
    const __bf16* __restrict__ Bh, const float* __restrict__ bias,
    __bf16* __restrict__ xlb, float* __restrict__ xrf,
    int M, int Kp, int N, int lognbx)
{
    __shared__ __align__(16) __bf16 sAh[128 * 32];
    __shared__ __align__(16) __bf16 sAl[128 * 32];
    __shared__ __align__(16) __bf16 sBh[128 * 32];

    const int tid  = threadIdx.x;
    const int lane = tid & 63;
    const int wave = tid >> 6;
    const int L    = blockIdx.x;
    const int xcd  = L & 7;
    const int t    = L >> 3;
    const int bx   = t & ((1 << lognbx) - 1);
    const int by   = xcd + 8 * (t >> lognbx);
    const int row0 = by * 128;
    const int col0 = bx * 128;
    const int wr = (wave >> 1) * 64;
    const int wc = (wave & 1) * 64;
    const int fm = lane & 15;
    const int fq = lane >> 4;

    f32x4 acc[4][4] = {};

    for (int k0 = 0; k0 < Kp; k0 += 32) {
#pragma unroll
        for (int it = 0; it < 2; ++it) {
            int c  = tid + it * 256;             // 0..511 16B chunks per tile
            int r  = c >> 2;
            int kc = (c & 3) ^ (r & 3);          // XOR swizzle
            size_t ga = (size_t)(row0 + r) * Kp + k0 + kc * 8;
            size_t gb = (size_t)(col0 + r) * Kp + k0 + kc * 8;
            __builtin_amdgcn_global_load_lds(
                (const __attribute__((address_space(1))) void*)(Ah + ga),
                (__attribute__((address_space(3))) void*)(sAh + c * 8), 16, 0, 0);
            __builtin_amdgcn_global_load_lds(
                (const __attribute__((address_space(1))) void*)(Al + ga),
                (__attribute__((address_space(3))) void*)(sAl + c * 8), 16, 0, 0);
            __builtin_amdgcn_global_load_lds(
                (const __attribute__((address_space(1))) void*)(Bh + gb),
                (__attribute__((address_space(3))) void*)(sBh + c * 8), 16, 0, 0);
        }
        __syncthreads();

        bf16x8 fah[4], fal[4], fbh[4];
#pragma unroll
        for (int mi = 0; mi < 4; ++mi) {
            int m = wr + mi * 16 + fm;
            int off = (m * 4 + (fq ^ (m & 3))) * 8;
            fah[mi] = *(const bf16x8*)(sAh + off);
            fal[mi] = *(const bf16x8*)(sAl + off);
        }
#pragma unroll
        for (int ni = 0; ni < 4; ++ni) {
            int n = wc + ni * 16 + fm;
            int off = (n * 4 + (fq ^ (n & 3))) * 8;
            fbh[ni] = *(const bf16x8*)(sBh + off);
        }
#pragma unroll
        for (int mi = 0; mi < 4; ++mi)
#pragma unroll
            for (int ni = 0; ni < 4; ++ni) {
                acc[mi][ni] = __builtin_amdgcn_mfma_f32_16x16x32_bf16(fah[mi], fbh[ni], acc[mi][ni], 0, 0, 0);
                acc[mi][ni] = __builtin_amdgcn_mfma_f32_16x16x32_bf16(fal[mi], fbh[ni], acc[mi][ni], 0, 0, 0);
            }
        __syncthreads();
    }

    const int NH = N >> 1;
    float bv[4];
#pragma unroll
    for (int ni = 0; ni < 4; ++ni) bv[ni] = bias[col0 + wc + ni * 16 + fm];
#pragma unroll
    for (int mi = 0; mi < 4; ++mi) {
        int grb = row0 + wr + mi * 16 + fq * 4;
#pragma unroll
        for (int reg = 0; reg < 4; ++reg) {
            int gr = grb + reg;
            if (gr < M) {
#pragma unroll
                for (int ni = 0; ni < 4; ++ni) {
                    int gc = col0 + wc + ni * 16 + fm;
                    float val = acc[mi][ni][reg] + bv[ni];
                    if (gc < NH) xlb[(size_t)gr * NH + gc] = (__bf16)val;
                    else         xrf[(size_t)gr * NH + gc - NH] = val;
                }
            }
        }
    }
}

// ---------- CSR build ----------
__global__ __launch_bounds__(256) void hist_kernel(
    const int* __restrict__ ei, int* __restrict__ deg)
{
    int e = blockIdx.x * blockDim.x + threadIdx.x;
    if (e >= ETOT) return;
    int d = (e < NEDGES) ? ei[NEDGES + e] : e - NEDGES;
    atomicAdd(&deg[d], 1);
}

__global__ __launch_bounds__(256) void scan_kernel(
    const int* __restrict__ deg, int* __restrict__ rowptr)
{
    __shared__ int partial[256];
    const int t = threadIdx.x;
    const int CH = (NNODES + 255) / 256;
    const int lo = t * CH, hi = min(lo + CH, NNODES);
    int s = 0;
    for (int i = lo; i < hi; i++) s += deg[i];
    partial[t] = s;
    __syncthreads();
    for (int off = 1; off < 256; off <<= 1) {
        int v = (t >= off) ? partial[t - off] : 0;
        __syncthreads();
        partial[t] += v;
        __syncthreads();
    }
    int run = partial[t] - s;
    for (int i = lo; i < hi; i++) { rowptr[i] = run; run += deg[i]; }
    if (t == 255) rowptr[NNODES] = partial[255];
}

__global__ __launch_bounds__(256) void scatter_kernel(
    const int* __restrict__ ei, const int* __restrict__ rowptr,
    int* __restrict__ cursor, int* __restrict__ perm_src)
{
    int e = blockIdx.x * blockDim.x + threadIdx.x;
    if (e >= ETOT) return;
    int s, d;
    if (e < NEDGES) { s = ei[e]; d = ei[NEDGES + e]; }
    else { s = e - NEDGES; d = s; }
    int pos = atomicAdd(&cursor[d], 1);
    perm_src[rowptr[d] + pos] = s;
}

// ---------- fused GATv2 edge phase: one wave per dst node, online softmax ----------
// xl is bf16 (written by GEMM epilogue), xr fp32. One 16B (P=8) or 4B (P=2)
// bf16 load per lane per edge.
template<int HC, int H>
__global__ __launch_bounds__(256) void gat_fused(
    const __bf16* __restrict__ xlb, const float* __restrict__ xrf,
    const float* __restrict__ att,
    const int* __restrict__ rowptr, const int* __restrict__ perm_src,
    float* __restrict__ out)
{
    constexpr int C = HC / H;
    constexpr int P = HC / 64;
    constexpr int GRP = C / P;
    const int lane = threadIdx.x & 63;
    const int wave = threadIdx.x >> 6;
    const int node = blockIdx.x * 4 + wave;
    if (node >= NNODES) return;

    const int base = lane * P;

    float xrv[P], w[P];
    const float* pr = xrf + (size_t)node * HC + base;
    if constexpr (P == 8) {
        *(float4*)(xrv)     = *(const float4*)(pr);
        *(float4*)(xrv + 4) = *(const float4*)(pr + 4);
        *(float4*)(w)       = *(const float4*)(att + base);
        *(float4*)(w + 4)   = *(const float4*)(att + base + 4);
    } else {
        *(float2*)(xrv) = *(const float2*)(pr);
        *(float2*)(w)   = *(const float2*)(att + base);
    }

    float m = -1e30f, l = 0.f;
    float acc[P];
#pragma unroll
    for (int j = 0; j < P; j++) acc[j] = 0.f;

    const int r0 = rowptr[node], r1 = rowptr[node + 1];
    for (int k = r0; k < r1; k++) {
        const int s = perm_src[k];
        const __bf16* pl = xlb + (size_t)s * HC + base;
        float a[P];
        if constexpr (P == 8) {
            bf16x8 ar = *(const bf16x8*)(pl);
#pragma unroll
            for (int j = 0; j < 8; j++) a[j] = (float)ar[j];
        } else {
            bf16x2 ar = *(const bf16x2*)(pl);
            a[0] = (float)ar[0]; a[1] = (float)ar[1];
        }
        float part = 0.f;
#pragma unroll
        for (int j = 0; j < P; j++) {
            float v = a[j] + xrv[j];
            v = v > 0.f ? v : v * NEG_SLOPE;
            part += v * w[j];
        }
#pragma unroll
        for (int off = GRP / 2; off > 0; off >>= 1) part += __shfl_xor(part, off);
        float mn = fmaxf(m, part);
        float scale = __expf(m - mn);
        float pe = __expf(part - mn);
        l = l * scale + pe;
#pragma unroll
        for (int j = 0; j < P; j++) acc[j] = acc[j] * scale + pe * a[j];
        m = mn;
    }
    const float inv = 1.f / l;
    float* po = out + (size_t)node * HC + base;
    if constexpr (P == 8) {
        float4 o0 = { acc[0] * inv, acc[1] * inv, acc[2] * inv, acc[3] * inv };
        float4 o1 = { acc[4] * inv, acc[5] * inv, acc[6] * inv, acc[7] * inv };
        *(float4*)(po)     = o0;
        *(float4*)(po + 4) = o1;
    } else {
        float2 o0 = { acc[0] * inv, acc[1] * inv };
        *(float2*)(po) = o0;
    }
}

// ---------- epilogue: +bo, LayerNorm, ELU ----------
// EMIT=true: write bf16 hi/lo (next layer's GEMM A), zero-fill pad rows (grid=MPAD)
// EMIT=false: write fp32 xout (final layer, grid=NNODES)
template<int HC, bool EMIT>
__global__ __launch_bounds__(128) void ln_elu(
    const float* __restrict__ hin, const float* __restrict__ bo,
    const float* __restrict__ gam, const float* __restrict__ bet,
    float* __restrict__ xout, __bf16* __restrict__ ah, __bf16* __restrict__ al)
{
    constexpr int T = 128, P = HC / T;
    int node = blockIdx.x, tid = threadIdx.x;
    if (EMIT && node >= NNODES) {
#pragma unroll
        for (int j = 0; j < P; j++) {
            size_t idx = (size_t)node * HC + tid + j * T;
            ah[idx] = (__bf16)0.f; al[idx] = (__bf16)0.f;
        }
        return;
    }
    const float* ph = hin + (size_t)node * HC;
    float v[P];
    float s = 0.f;
#pragma unroll
    for (int j = 0; j < P; j++) {
        int idx = tid + j * T;
        v[j] = ph[idx] + bo[idx];
        s += v[j];
    }
    __shared__ float red[2], red2[2];
#pragma unroll
    for (int off = 32; off > 0; off >>= 1) s += __shfl_xor(s, off);
    if ((tid & 63) == 0) red[tid >> 6] = s;
    __syncthreads();
    float mu = (red[0] + red[1]) / (float)HC;
    float q = 0.f;
#pragma unroll
    for (int j = 0; j < P; j++) { float dd = v[j] - mu; q += dd * dd; }
#pragma unroll
    for (int off = 32; off > 0; off >>= 1) q += __shfl_xor(q, off);
    if ((tid & 63) == 0) red2[tid >> 6] = q;
    __syncthreads();
    float rstd = rsqrtf((red2[0] + red2[1]) / (float)HC + LN_EPS);
#pragma unroll
    for (int j = 0; j < P; j++) {
        int idx = tid + j * T;
        float y = (v[j] - mu) * rstd * gam[idx] + bet[idx];
        y = y > 0.f ? y : expm1f(y);
        if (EMIT) {
            __bf16 h, l;
            bf16_split(y, h, l);
            ah[(size_t)node * HC + idx] = h;
            al[(size_t)node * HC + idx] = l;
        } else {
            xout[(size_t)node * HC + idx] = y;
        }
    }
}

// ---------- global mean pool ----------
__global__ __launch_bounds__(256) void pool_kernel(
    const float* __restrict__ x, const int* __restrict__ batch,
    float* __restrict__ sums, int* __restrict__ cnt)
{
    int idx = blockIdx.x * blockDim.x + threadIdx.x;
    if (idx >= NNODES * 128) return;
    int n = idx >> 7, c = idx & 127;
    int b = batch[n];
    atomicAdd(&sums[b * 128 + c], x[idx]);
    if (c == 0) atomicAdd(&cnt[b], 1);
}

// ---------- MLP head ----------
__global__ __launch_bounds__(128) void mlp_kernel(
    const float* __restrict__ sums, const int* __restrict__ cnt,
    const float* __restrict__ W1, const float* __restrict__ b1,
    const float* __restrict__ W2, const float* __restrict__ b2,
    const float* __restrict__ W3, const float* __restrict__ b3,
    float* __restrict__ out)
{
    __shared__ float pool[128], h1[128], h2[64];
    int g = blockIdx.x, t = threadIdx.x;
    float c = (float)max(cnt[g], 1);
    pool[t] = sums[g * 128 + t] / c;
    __syncthreads();
    float a = b1[t];
    for (int k = 0; k < 128; k++) a += pool[k] * W1[k * 128 + t];
    h1[t] = fmaxf(a, 0.f);
    __syncthreads();
    if (t < 64) {
        float a2 = b2[t];
        for (int k = 0; k < 128; k++) a2 += h1[k] * W2[k * 64 + t];
        h2[t] = fmaxf(a2, 0.f);
    }
    __syncthreads();
    if (t == 0) {
        float a3 = b3[0];
        for (int k = 0; k < 64; k++) a3 += h2[k] * W3[k];
        out[g] = a3;
    }
}

// =====================================================================
extern "C" void kernel_launch(void* const* d_in, const int* in_sizes, int n_in,
                              void* d_out, int out_size, void* d_ws, size_t ws_size,
                              hipStream_t stream)
{
    const float* x     = (const float*)d_in[0];
    const int*   ei    = (const int*)d_in[1];
    const int*   batch = (const int*)d_in[2];

    const float *Wl[3], *bl[3], *Wr[3], *br[3], *att[3], *bo[3], *ga[3], *be[3];
    for (int l = 0; l < 3; l++) {
        int o = 3 + l * 8;
        Wl[l]  = (const float*)d_in[o + 0];
        bl[l]  = (const float*)d_in[o + 1];
        Wr[l]  = (const float*)d_in[o + 2];
        br[l]  = (const float*)d_in[o + 3];
        att[l] = (const float*)d_in[o + 4];
        bo[l]  = (const float*)d_in[o + 5];
        ga[l]  = (const float*)d_in[o + 6];
        be[l]  = (const float*)d_in[o + 7];
    }
    const float* W1 = (const float*)d_in[27];
    const float* b1 = (const float*)d_in[28];
    const float* W2 = (const float*)d_in[29];
    const float* b2 = (const float*)d_in[30];
    const float* W3 = (const float*)d_in[31];
    const float* b3 = (const float*)d_in[32];

    // workspace layout
    char* w = (char*)d_ws;
    size_t off = 0;
    auto alloc = [&](size_t bytes) {
        void* p = w + off;
        off += (bytes + 255) & ~(size_t)255;
        return p;
    };
    __bf16* xlb   = (__bf16*)alloc((size_t)NNODES * 512 * 2);      // xl (bf16) from GEMM
    float*  xrf   = (float*)alloc((size_t)NNODES * 512 * 4);       // xr (fp32) from GEMM
    float*  hbuf  = (float*)alloc((size_t)NNODES * 512 * 4);       // gat output
    float*  xfin  = (float*)alloc((size_t)NNODES * 128 * 4);       // final layer fp32
    __bf16* Axh   = (__bf16*)alloc((size_t)MPAD * 800 * 2);        // A hi (reused [MPAD][512] for layers 1/2)
    __bf16* Axl   = (__bf16*)alloc((size_t)MPAD * 800 * 2);
    __bf16* Bh0   = (__bf16*)alloc((size_t)1024 * 800 * 2);
    __bf16* Bh1   = (__bf16*)alloc((size_t)1024 * 512 * 2);
    __bf16* Bh2   = (__bf16*)alloc((size_t)256 * 512 * 2);
    float*  bp0   = (float*)alloc(1024 * 4);
    float*  bp1   = (float*)alloc(1024 * 4);
    float*  bp2   = (float*)alloc(256 * 4);
    int*    deg      = (int*)alloc((size_t)NNODES * 4);
    int*    rowptr   = (int*)alloc((size_t)(NNODES + 1) * 4);
    int*    cursor   = (int*)alloc((size_t)NNODES * 4);
    int*    perm_src = (int*)alloc((size_t)ETOT * 4);
    float*  psum     = (float*)alloc((size_t)NGRAPH * 128 * 4);
    int*    pcnt     = (int*)alloc((size_t)NGRAPH * 4);
    __bf16* Ah1 = Axh;   // [MPAD][512] for layers 1/2
    __bf16* Al1 = Axl;

    // ---- input conversion + weight packing ----
    convert_x<<<(MPAD * 800 + 255) / 256, 256, 0, stream>>>(x, Axh, Axl);
    pack_w<<<(1024 * 800 + 255) / 256, 256, 0, stream>>>(Wl[0], Wr[0], bl[0], br[0], Bh0, bp0, 771, 800, 512, 1024);
    pack_w<<<(1024 * 512 + 255) / 256, 256, 0, stream>>>(Wl[1], Wr[1], bl[1], br[1], Bh1, bp1, 512, 512, 512, 1024);
    pack_w<<<(256 * 512 + 255) / 256, 256, 0, stream>>>(Wl[2], Wr[2], bl[2], br[2], Bh2, bp2, 512, 512, 128, 256);

    // ---- build CSR by destination ----
    hipMemsetAsync(deg, 0, (size_t)NNODES * 4, stream);
    hipMemsetAsync(cursor, 0, (size_t)NNODES * 4, stream);
    hist_kernel<<<(ETOT + 255) / 256, 256, 0, stream>>>(ei, deg);
    scan_kernel<<<1, 256, 0, stream>>>(deg, rowptr);
    scatter_kernel<<<(ETOT + 255) / 256, 256, 0, stream>>>(ei, rowptr, cursor, perm_src);

    const int fgrid = (NNODES + 3) / 4;

    // ---- layer 0: [10000,771] x [771,1024] ----
    gemm_mfma<<<80 * 8, 256, 0, stream>>>(Axh, Axl, Bh0, bp0, xlb, xrf, NNODES, 800, 1024, 3);
    gat_fused<512, 4><<<fgrid, 256, 0, stream>>>(xlb, xrf, att[0], rowptr, perm_src, hbuf);
    ln_elu<512, true><<<MPAD, 128, 0, stream>>>(hbuf, bo[0], ga[0], be[0], nullptr, Ah1, Al1);

    // ---- layer 1: [10000,512] x [512,1024] ----
    gemm_mfma<<<80 * 8, 256, 0, stream>>>(Ah1, Al1, Bh1, bp1, xlb, xrf, NNODES, 512, 1024, 3);
    gat_fused<512, 4><<<fgrid, 256, 0, stream>>>(xlb, xrf, att[1], rowptr, perm_src, hbuf);
    ln_elu<512, true><<<MPAD, 128, 0, stream>>>(hbuf, bo[1], ga[1], be[1], nullptr, Ah1, Al1);

    // ---- layer 2: [10000,512] x [512,256] ----
    gemm_mfma<<<80 * 2, 256, 0, stream>>>(Ah1, Al1, Bh2, bp2, xlb, xrf, NNODES, 512, 256, 1);
    gat_fused<128, 1><<<fgrid, 256, 0, stream>>>(xlb, xrf, att[2], rowptr, perm_src, hbuf);
    ln_elu<128, false><<<NNODES, 128, 0, stream>>>(hbuf, bo[2], ga[2], be[2], xfin, nullptr, nullptr);

    // ---- pool + MLP ----
    hipMemsetAsync(psum, 0, (size_t)NGRAPH * 128 * 4, stream);
    hipMemsetAsync(pcnt, 0, (size_t)NGRAPH * 4, stream);
    pool_kernel<<<(NNODES * 128 + 255) / 256, 256, 0, stream>>>(xfin, batch, psum, pcnt);
    mlp_kernel<<<NGRAPH, 128, 0, stream>>>(psum, pcnt, W1, b1, W2, b2, W3, b3, (float*)d_out);
}

// Round 5
// 447.571 us; speedup vs baseline: 13.3331x; 1.1624x over previous
//
#include <hip/hip_runtime.h>
#include <math.h>

#define NNODES 10000
#define MPAD   10240               // 80*128, padded row count for MFMA GEMM
#define NEDGES 160000
#define ETOT   (NEDGES + NNODES)   // 170000, with self loops
#define NGRAPH 64
#define LN_EPS 1e-5f
#define NEG_SLOPE 0.2f

typedef __bf16 bf16x8 __attribute__((ext_vector_type(8)));
typedef __bf16 bf16x2 __attribute__((ext_vector_type(2)));
typedef float  f32x4  __attribute__((ext_vector_type(4)));

// ---------- split a fp32 into hi/lo bf16 ----------
__device__ __forceinline__ void bf16_split(float v, __bf16& h, __bf16& l) {
    __bf16 bh = (__bf16)v;
    float  fh = (float)bh;
    h = bh;
    l = (__bf16)(v - fh);
}

// ---------- convert x [10000][771] fp32 -> Ah/Al [MPAD][800] bf16 (zero pad) ----------
__global__ __launch_bounds__(256) void convert_x(
    const float* __restrict__ x, __bf16* __restrict__ ah, __bf16* __restrict__ al)
{
    int idx = blockIdx.x * blockDim.x + threadIdx.x;
    if (idx >= MPAD * 800) return;
    int r = idx / 800, k = idx - r * 800;
    float v = (r < NNODES && k < 771) ? x[(size_t)r * 771 + k] : 0.f;
    __bf16 h, l;
    bf16_split(v, h, l);
    ah[idx] = h; al[idx] = l;
}

// ---------- pack weights: Wl|Wr [K][NW] -> Bh [Np][Kp] bf16 transposed (hi only) ----------
__global__ __launch_bounds__(256) void pack_w(
    const float* __restrict__ Wl, const float* __restrict__ Wr,
    const float* __restrict__ bl, const float* __restrict__ br,
    __bf16* __restrict__ bh, float* __restrict__ biasp,
    int K, int Kp, int NW, int Np)
{
    int idx = blockIdx.x * blockDim.x + threadIdx.x;
    if (idx < Np) biasp[idx] = (idx < NW) ? bl[idx] : br[idx - NW];
    if (idx >= Np * Kp) return;
    int n = idx / Kp, k = idx - n * Kp;
    float v = 0.f;
    if (k < K) v = (n < NW) ? Wl[(size_t)k * NW + n] : Wr[(size_t)k * NW + (n - NW)];
    bh[idx] = (__bf16)v;
}

// ---------- 2-term split MFMA GEMM: C = (Ah+Al) @ Bh + bias ----------
// 128x128 tile, 4 waves x 64x64, BK=32, 16x16x32 MFMA, XOR-swizzled LDS,
// XCD-aware 1-D grid. Epilogue: cols < N/2 -> xl bf16; cols >= N/2 -> xr fp32.
__global__ __launch_bounds__(256) void gemm_mfma(
    const __bf16* __restrict__ Ah, const __bf16* __restrict__ Al,
    const __bf16* __restrict__ Bh, const float* __restrict__ bias,
    __bf16* __restrict__ xlb, float* __restrict__ xrf,
    int M, int Kp, int N, int lognbx)
{
    __shared__ __align__(16) __bf16 sAh[128 * 32];
    __shared__ __align__(16) __bf16 sAl[128 * 32];
    __shared__ __align__(16) __bf16 sBh[128 * 32];

    const int tid  = threadIdx.x;
    const int lane = tid & 63;
    const int wave = tid >> 6;
    const int L    = blockIdx.x;
    const int xcd  = L & 7;
    const int t    = L >> 3;
    const int bx   = t & ((1 << lognbx) - 1);
    const int by   = xcd + 8 * (t >> lognbx);
    const int row0 = by * 128;
    const int col0 = bx * 128;
    const int wr = (wave >> 1) * 64;
    const int wc = (wave & 1) * 64;
    const int fm = lane & 15;
    const int fq = lane >> 4;

    f32x4 acc[4][4] = {};

    for (int k0 = 0; k0 < Kp; k0 += 32) {
#pragma unroll
        for (int it = 0; it < 2; ++it) {
            int c  = tid + it * 256;
            int r  = c >> 2;
            int kc = (c & 3) ^ (r & 3);
            size_t ga = (size_t)(row0 + r) * Kp + k0 + kc * 8;
            size_t gb = (size_t)(col0 + r) * Kp + k0 + kc * 8;
            __builtin_amdgcn_global_load_lds(
                (const __attribute__((address_space(1))) void*)(Ah + ga),
                (__attribute__((address_space(3))) void*)(sAh + c * 8), 16, 0, 0);
            __builtin_amdgcn_global_load_lds(
                (const __attribute__((address_space(1))) void*)(Al + ga),
                (__attribute__((address_space(3))) void*)(sAl + c * 8), 16, 0, 0);
            __builtin_amdgcn_global_load_lds(
                (const __attribute__((address_space(1))) void*)(Bh + gb),
                (__attribute__((address_space(3))) void*)(sBh + c * 8), 16, 0, 0);
        }
        __syncthreads();

        bf16x8 fah[4], fal[4], fbh[4];
#pragma unroll
        for (int mi = 0; mi < 4; ++mi) {
            int m = wr + mi * 16 + fm;
            int off = (m * 4 + (fq ^ (m & 3))) * 8;
            fah[mi] = *(const bf16x8*)(sAh + off);
            fal[mi] = *(const bf16x8*)(sAl + off);
        }
#pragma unroll
        for (int ni = 0; ni < 4; ++ni) {
            int n = wc + ni * 16 + fm;
            int off = (n * 4 + (fq ^ (n & 3))) * 8;
            fbh[ni] = *(const bf16x8*)(sBh + off);
        }
#pragma unroll
        for (int mi = 0; mi < 4; ++mi)
#pragma unroll
            for (int ni = 0; ni < 4; ++ni) {
                acc[mi][ni] = __builtin_amdgcn_mfma_f32_16x16x32_bf16(fah[mi], fbh[ni], acc[mi][ni], 0, 0, 0);
                acc[mi][ni] = __builtin_amdgcn_mfma_f32_16x16x32_bf16(fal[mi], fbh[ni], acc[mi][ni], 0, 0, 0);
            }
        __syncthreads();
    }

    const int NH = N >> 1;
    float bv[4];
#pragma unroll
    for (int ni = 0; ni < 4; ++ni) bv[ni] = bias[col0 + wc + ni * 16 + fm];
#pragma unroll
    for (int mi = 0; mi < 4; ++mi) {
        int grb = row0 + wr + mi * 16 + fq * 4;
#pragma unroll
        for (int reg = 0; reg < 4; ++reg) {
            int gr = grb + reg;
            if (gr < M) {
#pragma unroll
                for (int ni = 0; ni < 4; ++ni) {
                    int gc = col0 + wc + ni * 16 + fm;
                    float val = acc[mi][ni][reg] + bv[ni];
                    if (gc < NH) xlb[(size_t)gr * NH + gc] = (__bf16)val;
                    else         xrf[(size_t)gr * NH + gc - NH] = val;
                }
            }
        }
    }
}

// ---------- CSR build ----------
__global__ __launch_bounds__(256) void hist_kernel(
    const int* __restrict__ ei, int* __restrict__ deg)
{
    int e = blockIdx.x * blockDim.x + threadIdx.x;
    if (e >= ETOT) return;
    int d = (e < NEDGES) ? ei[NEDGES + e] : e - NEDGES;
    atomicAdd(&deg[d], 1);
}

__global__ __launch_bounds__(256) void scan_kernel(
    const int* __restrict__ deg, int* __restrict__ rowptr)
{
    __shared__ int partial[256];
    const int t = threadIdx.x;
    const int CH = (NNODES + 255) / 256;
    const int lo = t * CH, hi = min(lo + CH, NNODES);
    int s = 0;
    for (int i = lo; i < hi; i++) s += deg[i];
    partial[t] = s;
    __syncthreads();
    for (int off = 1; off < 256; off <<= 1) {
        int v = (t >= off) ? partial[t - off] : 0;
        __syncthreads();
        partial[t] += v;
        __syncthreads();
    }
    int run = partial[t] - s;
    for (int i = lo; i < hi; i++) { rowptr[i] = run; run += deg[i]; }
    if (t == 255) rowptr[NNODES] = partial[255];
}

__global__ __launch_bounds__(256) void scatter_kernel(
    const int* __restrict__ ei, const int* __restrict__ rowptr,
    int* __restrict__ cursor, int* __restrict__ perm_src)
{
    int e = blockIdx.x * blockDim.x + threadIdx.x;
    if (e >= ETOT) return;
    int s, d;
    if (e < NEDGES) { s = ei[e]; d = ei[NEDGES + e]; }
    else { s = e - NEDGES; d = s; }
    int pos = atomicAdd(&cursor[d], 1);
    perm_src[rowptr[d] + pos] = s;
}

// ---------- fused GATv2 edge phase + bias + LayerNorm + ELU ----------
// One wave per dst node: online softmax over incoming edges, then LN across
// the wave's registers (full 64-lane shuffle reduce), ELU, and either
// bf16 hi/lo emit (next layer's GEMM A, grid covers MPAD: pad rows zeroed)
// or fp32 emit (final layer).
template<int HC, int H, bool EMIT>
__global__ __launch_bounds__(256) void gat_ln(
    const __bf16* __restrict__ xlb, const float* __restrict__ xrf,
    const float* __restrict__ att, const float* __restrict__ bo,
    const float* __restrict__ gam, const float* __restrict__ bet,
    const int* __restrict__ rowptr, const int* __restrict__ perm_src,
    float* __restrict__ xout, __bf16* __restrict__ ah, __bf16* __restrict__ al)
{
    constexpr int C = HC / H;
    constexpr int P = HC / 64;
    constexpr int GRP = C / P;
    const int lane = threadIdx.x & 63;
    const int wave = threadIdx.x >> 6;
    const int node = blockIdx.x * 4 + wave;
    const int base = lane * P;

    if (EMIT && node >= NNODES) {       // zero GEMM pad rows
        if (node < MPAD) {
            bf16x8 z = {};
            *(bf16x8*)(ah + (size_t)node * HC + base) = z;
            *(bf16x8*)(al + (size_t)node * HC + base) = z;
        }
        return;
    }
    if (node >= NNODES) return;

    float xrv[P], w[P];
    const float* pr = xrf + (size_t)node * HC + base;
    if constexpr (P == 8) {
        *(float4*)(xrv)     = *(const float4*)(pr);
        *(float4*)(xrv + 4) = *(const float4*)(pr + 4);
        *(float4*)(w)       = *(const float4*)(att + base);
        *(float4*)(w + 4)   = *(const float4*)(att + base + 4);
    } else {
        *(float2*)(xrv) = *(const float2*)(pr);
        *(float2*)(w)   = *(const float2*)(att + base);
    }

    float m = -1e30f, l = 0.f;
    float acc[P];
#pragma unroll
    for (int j = 0; j < P; j++) acc[j] = 0.f;

    const int r0 = rowptr[node], r1 = rowptr[node + 1];
    for (int k = r0; k < r1; k++) {
        const int s = perm_src[k];
        const __bf16* pl = xlb + (size_t)s * HC + base;
        float a[P];
        if constexpr (P == 8) {
            bf16x8 ar = *(const bf16x8*)(pl);
#pragma unroll
            for (int j = 0; j < 8; j++) a[j] = (float)ar[j];
        } else {
            bf16x2 ar = *(const bf16x2*)(pl);
            a[0] = (float)ar[0]; a[1] = (float)ar[1];
        }
        float part = 0.f;
#pragma unroll
        for (int j = 0; j < P; j++) {
            float v = a[j] + xrv[j];
            v = v > 0.f ? v : v * NEG_SLOPE;
            part += v * w[j];
        }
#pragma unroll
        for (int off = GRP / 2; off > 0; off >>= 1) part += __shfl_xor(part, off);
        float mn = fmaxf(m, part);
        float scale = __expf(m - mn);
        float pe = __expf(part - mn);
        l = l * scale + pe;
#pragma unroll
        for (int j = 0; j < P; j++) acc[j] = acc[j] * scale + pe * a[j];
        m = mn;
    }
    const float inv = 1.f / l;

    // ---- LayerNorm across the wave (all HC channels of this node) ----
    float v[P];
    float s = 0.f;
#pragma unroll
    for (int j = 0; j < P; j++) {
        v[j] = acc[j] * inv + bo[base + j];
        s += v[j];
    }
#pragma unroll
    for (int off = 1; off < 64; off <<= 1) s += __shfl_xor(s, off);
    const float mu = s / (float)HC;
    float q = 0.f;
#pragma unroll
    for (int j = 0; j < P; j++) { float dd = v[j] - mu; q += dd * dd; }
#pragma unroll
    for (int off = 1; off < 64; off <<= 1) q += __shfl_xor(q, off);
    const float rstd = rsqrtf(q / (float)HC + LN_EPS);

    float gmv[P], btv[P];
    if constexpr (P == 8) {
        *(float4*)(gmv)     = *(const float4*)(gam + base);
        *(float4*)(gmv + 4) = *(const float4*)(gam + base + 4);
        *(float4*)(btv)     = *(const float4*)(bet + base);
        *(float4*)(btv + 4) = *(const float4*)(bet + base + 4);
    } else {
        *(float2*)(gmv) = *(const float2*)(gam + base);
        *(float2*)(btv) = *(const float2*)(bet + base);
    }

    if constexpr (EMIT) {
        bf16x8 hv, lv;
#pragma unroll
        for (int j = 0; j < P; j++) {
            float y = (v[j] - mu) * rstd * gmv[j] + btv[j];
            y = y > 0.f ? y : expm1f(y);
            __bf16 h, lo2;
            bf16_split(y, h, lo2);
            hv[j] = h; lv[j] = lo2;
        }
        *(bf16x8*)(ah + (size_t)node * HC + base) = hv;
        *(bf16x8*)(al + (size_t)node * HC + base) = lv;
    } else {
        float o[P];
#pragma unroll
        for (int j = 0; j < P; j++) {
            float y = (v[j] - mu) * rstd * gmv[j] + btv[j];
            o[j] = y > 0.f ? y : expm1f(y);
        }
        if constexpr (P == 2) {
            float2 o0 = { o[0], o[1] };
            *(float2*)(xout + (size_t)node * HC + base) = o0;
        } else {
            float4 o0 = { o[0], o[1], o[2], o[3] };
            float4 o1 = { o[4], o[5], o[6], o[7] };
            *(float4*)(xout + (size_t)node * HC + base) = o0;
            *(float4*)(xout + (size_t)node * HC + base + 4) = o1;
        }
    }
}

// ---------- fused mean-pool (segmented, no atomics) + MLP head ----------
// batch is sorted; block g binary-searches its node range, sums, then MLP.
__global__ __launch_bounds__(128) void pool_mlp(
    const float* __restrict__ xfin, const int* __restrict__ batch,
    const float* __restrict__ W1, const float* __restrict__ b1,
    const float* __restrict__ W2, const float* __restrict__ b2,
    const float* __restrict__ W3, const float* __restrict__ b3,
    float* __restrict__ out)
{
    __shared__ int bounds[2];
    __shared__ float pool[128], h1[128], h2[64];
    const int g = blockIdx.x, t = threadIdx.x;
    if (t < 2) {
        int target = g + t;          // lower_bound(batch, target)
        int lo = 0, hi = NNODES;
        while (lo < hi) { int mid = (lo + hi) >> 1; if (batch[mid] < target) lo = mid + 1; else hi = mid; }
        bounds[t] = lo;
    }
    __syncthreads();
    const int lo = bounds[0], hi = bounds[1];
    float s = 0.f;
#pragma unroll 4
    for (int n = lo; n < hi; n++) s += xfin[(size_t)n * 128 + t];
    pool[t] = s / (float)max(hi - lo, 1);
    __syncthreads();
    float a = b1[t];
    for (int k = 0; k < 128; k++) a += pool[k] * W1[k * 128 + t];
    h1[t] = fmaxf(a, 0.f);
    __syncthreads();
    if (t < 64) {
        float a2 = b2[t];
        for (int k = 0; k < 128; k++) a2 += h1[k] * W2[k * 64 + t];
        h2[t] = fmaxf(a2, 0.f);
    }
    __syncthreads();
    if (t == 0) {
        float a3 = b3[0];
        for (int k = 0; k < 64; k++) a3 += h2[k] * W3[k];
        out[g] = a3;
    }
}

// =====================================================================
extern "C" void kernel_launch(void* const* d_in, const int* in_sizes, int n_in,
                              void* d_out, int out_size, void* d_ws, size_t ws_size,
                              hipStream_t stream)
{
    const float* x     = (const float*)d_in[0];
    const int*   ei    = (const int*)d_in[1];
    const int*   batch = (const int*)d_in[2];

    const float *Wl[3], *bl[3], *Wr[3], *br[3], *att[3], *bo[3], *ga[3], *be[3];
    for (int l = 0; l < 3; l++) {
        int o = 3 + l * 8;
        Wl[l]  = (const float*)d_in[o + 0];
        bl[l]  = (const float*)d_in[o + 1];
        Wr[l]  = (const float*)d_in[o + 2];
        br[l]  = (const float*)d_in[o + 3];
        att[l] = (const float*)d_in[o + 4];
        bo[l]  = (const float*)d_in[o + 5];
        ga[l]  = (const float*)d_in[o + 6];
        be[l]  = (const float*)d_in[o + 7];
    }
    const float* W1 = (const float*)d_in[27];
    const float* b1 = (const float*)d_in[28];
    const float* W2 = (const float*)d_in[29];
    const float* b2 = (const float*)d_in[30];
    const float* W3 = (const float*)d_in[31];
    const float* b3 = (const float*)d_in[32];

    // workspace layout
    char* w = (char*)d_ws;
    size_t off = 0;
    auto alloc = [&](size_t bytes) {
        void* p = w + off;
        off += (bytes + 255) & ~(size_t)255;
        return p;
    };
    __bf16* xlb   = (__bf16*)alloc((size_t)NNODES * 512 * 2);      // xl (bf16) from GEMM
    float*  xrf   = (float*)alloc((size_t)NNODES * 512 * 4);       // xr (fp32) from GEMM
    float*  xfin  = (float*)alloc((size_t)NNODES * 128 * 4);       // final layer fp32
    __bf16* Axh   = (__bf16*)alloc((size_t)MPAD * 800 * 2);        // A hi (reused [MPAD][512] for layers 1/2)
    __bf16* Axl   = (__bf16*)alloc((size_t)MPAD * 800 * 2);
    __bf16* Bh0   = (__bf16*)alloc((size_t)1024 * 800 * 2);
    __bf16* Bh1   = (__bf16*)alloc((size_t)1024 * 512 * 2);
    __bf16* Bh2   = (__bf16*)alloc((size_t)256 * 512 * 2);
    float*  bp0   = (float*)alloc(1024 * 4);
    float*  bp1   = (float*)alloc(1024 * 4);
    float*  bp2   = (float*)alloc(256 * 4);
    int*    deg      = (int*)alloc((size_t)NNODES * 4);
    int*    rowptr   = (int*)alloc((size_t)(NNODES + 1) * 4);
    int*    cursor   = (int*)alloc((size_t)NNODES * 4);
    int*    perm_src = (int*)alloc((size_t)ETOT * 4);
    __bf16* Ah1 = Axh;   // [MPAD][512] for layers 1/2
    __bf16* Al1 = Axl;

    // ---- input conversion + weight packing ----
    convert_x<<<(MPAD * 800 + 255) / 256, 256, 0, stream>>>(x, Axh, Axl);
    pack_w<<<(1024 * 800 + 255) / 256, 256, 0, stream>>>(Wl[0], Wr[0], bl[0], br[0], Bh0, bp0, 771, 800, 512, 1024);
    pack_w<<<(1024 * 512 + 255) / 256, 256, 0, stream>>>(Wl[1], Wr[1], bl[1], br[1], Bh1, bp1, 512, 512, 512, 1024);
    pack_w<<<(256 * 512 + 255) / 256, 256, 0, stream>>>(Wl[2], Wr[2], bl[2], br[2], Bh2, bp2, 512, 512, 128, 256);

    // ---- build CSR by destination ----
    hipMemsetAsync(deg, 0, (size_t)NNODES * 4, stream);
    hipMemsetAsync(cursor, 0, (size_t)NNODES * 4, stream);
    hist_kernel<<<(ETOT + 255) / 256, 256, 0, stream>>>(ei, deg);
    scan_kernel<<<1, 256, 0, stream>>>(deg, rowptr);
    scatter_kernel<<<(ETOT + 255) / 256, 256, 0, stream>>>(ei, rowptr, cursor, perm_src);

    const int fgrid_pad = (MPAD + 3) / 4;     // covers pad rows for bf16 emit
    const int fgrid     = (NNODES + 3) / 4;

    // ---- layer 0: [10000,771] x [771,1024] ----
    gemm_mfma<<<80 * 8, 256, 0, stream>>>(Axh, Axl, Bh0, bp0, xlb, xrf, NNODES, 800, 1024, 3);
    gat_ln<512, 4, true><<<fgrid_pad, 256, 0, stream>>>(
        xlb, xrf, att[0], bo[0], ga[0], be[0], rowptr, perm_src, nullptr, Ah1, Al1);

    // ---- layer 1: [10000,512] x [512,1024] ----
    gemm_mfma<<<80 * 8, 256, 0, stream>>>(Ah1, Al1, Bh1, bp1, xlb, xrf, NNODES, 512, 1024, 3);
    gat_ln<512, 4, true><<<fgrid_pad, 256, 0, stream>>>(
        xlb, xrf, att[1], bo[1], ga[1], be[1], rowptr, perm_src, nullptr, Ah1, Al1);

    // ---- layer 2: [10000,512] x [512,256] ----
    gemm_mfma<<<80 * 2, 256, 0, stream>>>(Ah1, Al1, Bh2, bp2, xlb, xrf, NNODES, 512, 256, 1);
    gat_ln<128, 1, false><<<fgrid, 256, 0, stream>>>(
        xlb, xrf, att[2], bo[2], ga[2], be[2], rowptr, perm_src, xfin, nullptr, nullptr);

    // ---- fused pool + MLP ----
    pool_mlp<<<NGRAPH, 128, 0, stream>>>(xfin, batch, W1, b1, W2, b2, W3, b3, (float*)d_out);
}

// Round 6
// 420.487 us; speedup vs baseline: 14.1919x; 1.0644x over previous
//
#include <hip/hip_runtime.h>
#include <math.h>

#define NNODES 10000
#define MPAD   10240               // 80*128, padded row count for MFMA GEMM
#define NEDGES 160000
#define ETOT   (NEDGES + NNODES)   // 170000, with self loops
#define NGRAPH 64
#define LN_EPS 1e-5f
#define NEG_SLOPE 0.2f

typedef __bf16 bf16x8 __attribute__((ext_vector_type(8)));
typedef __bf16 bf16x2 __attribute__((ext_vector_type(2)));
typedef float  f32x4  __attribute__((ext_vector_type(4)));

// ---------- split a fp32 into hi/lo bf16 ----------
__device__ __forceinline__ void bf16_split(float v, __bf16& h, __bf16& l) {
    __bf16 bh = (__bf16)v;
    float  fh = (float)bh;
    h = bh;
    l = (__bf16)(v - fh);
}

// ---------- convert x [10000][771] fp32 -> Ah/Al [MPAD][800] bf16 (zero pad) ----------
__global__ __launch_bounds__(256) void convert_x(
    const float* __restrict__ x, __bf16* __restrict__ ah, __bf16* __restrict__ al)
{
    int idx = blockIdx.x * blockDim.x + threadIdx.x;
    if (idx >= MPAD * 800) return;
    int r = idx / 800, k = idx - r * 800;
    float v = (r < NNODES && k < 771) ? x[(size_t)r * 771 + k] : 0.f;
    __bf16 h, l;
    bf16_split(v, h, l);
    ah[idx] = h; al[idx] = l;
}

// ---------- pack weights: Wl|Wr [K][NW] -> Bh [Np][Kp] bf16 transposed (hi only) ----------
__global__ __launch_bounds__(256) void pack_w(
    const float* __restrict__ Wl, const float* __restrict__ Wr,
    const float* __restrict__ bl, const float* __restrict__ br,
    __bf16* __restrict__ bh, float* __restrict__ biasp,
    int K, int Kp, int NW, int Np)
{
    int idx = blockIdx.x * blockDim.x + threadIdx.x;
    if (idx < Np) biasp[idx] = (idx < NW) ? bl[idx] : br[idx - NW];
    if (idx >= Np * Kp) return;
    int n = idx / Kp, k = idx - n * Kp;
    float v = 0.f;
    if (k < K) v = (n < NW) ? Wl[(size_t)k * NW + n] : Wr[(size_t)k * NW + (n - NW)];
    bh[idx] = (__bf16)v;
}

// ---------- 2-term split MFMA GEMM: C = (Ah+Al) @ Bh + bias ----------
// 128x128 tile, 4 waves x 64x64, BK=32, 16x16x32 MFMA, XOR-swizzled LDS,
// XCD-aware 1-D grid. Epilogue: cols < N/2 -> xl bf16; cols >= N/2 -> xr fp32.
__global__ __launch_bounds__(256) void gemm_mfma(
    const __bf16* __restrict__ Ah, const __bf16* __restrict__ Al,
    const __bf16* __restrict__ Bh, const float* __restrict__ bias,
    __bf16* __restrict__ xlb, float* __restrict__ xrf,
    int M, int Kp, int N, int lognbx)
{
    __shared__ __align__(16) __bf16 sAh[128 * 32];
    __shared__ __align__(16) __bf16 sAl[128 * 32];
    __shared__ __align__(16) __bf16 sBh[128 * 32];

    const int tid  = threadIdx.x;
    const int lane = tid & 63;
    const int wave = tid >> 6;
    const int L    = blockIdx.x;
    const int xcd  = L & 7;
    const int t    = L >> 3;
    const int bx   = t & ((1 << lognbx) - 1);
    const int by   = xcd + 8 * (t >> lognbx);
    const int row0 = by * 128;
    const int col0 = bx * 128;
    const int wr = (wave >> 1) * 64;
    const int wc = (wave & 1) * 64;
    const int fm = lane & 15;
    const int fq = lane >> 4;

    f32x4 acc[4][4] = {};

    for (int k0 = 0; k0 < Kp; k0 += 32) {
#pragma unroll
        for (int it = 0; it < 2; ++it) {
            int c  = tid + it * 256;
            int r  = c >> 2;
            int kc = (c & 3) ^ (r & 3);
            size_t ga = (size_t)(row0 + r) * Kp + k0 + kc * 8;
            size_t gb = (size_t)(col0 + r) * Kp + k0 + kc * 8;
            __builtin_amdgcn_global_load_lds(
                (const __attribute__((address_space(1))) void*)(Ah + ga),
                (__attribute__((address_space(3))) void*)(sAh + c * 8), 16, 0, 0);
            __builtin_amdgcn_global_load_lds(
                (const __attribute__((address_space(1))) void*)(Al + ga),
                (__attribute__((address_space(3))) void*)(sAl + c * 8), 16, 0, 0);
            __builtin_amdgcn_global_load_lds(
                (const __attribute__((address_space(1))) void*)(Bh + gb),
                (__attribute__((address_space(3))) void*)(sBh + c * 8), 16, 0, 0);
        }
        __syncthreads();

        bf16x8 fah[4], fal[4], fbh[4];
#pragma unroll
        for (int mi = 0; mi < 4; ++mi) {
            int m = wr + mi * 16 + fm;
            int off = (m * 4 + (fq ^ (m & 3))) * 8;
            fah[mi] = *(const bf16x8*)(sAh + off);
            fal[mi] = *(const bf16x8*)(sAl + off);
        }
#pragma unroll
        for (int ni = 0; ni < 4; ++ni) {
            int n = wc + ni * 16 + fm;
            int off = (n * 4 + (fq ^ (n & 3))) * 8;
            fbh[ni] = *(const bf16x8*)(sBh + off);
        }
#pragma unroll
        for (int mi = 0; mi < 4; ++mi)
#pragma unroll
            for (int ni = 0; ni < 4; ++ni) {
                acc[mi][ni] = __builtin_amdgcn_mfma_f32_16x16x32_bf16(fah[mi], fbh[ni], acc[mi][ni], 0, 0, 0);
                acc[mi][ni] = __builtin_amdgcn_mfma_f32_16x16x32_bf16(fal[mi], fbh[ni], acc[mi][ni], 0, 0, 0);
            }
        __syncthreads();
    }

    const int NH = N >> 1;
    float bv[4];
#pragma unroll
    for (int ni = 0; ni < 4; ++ni) bv[ni] = bias[col0 + wc + ni * 16 + fm];
#pragma unroll
    for (int mi = 0; mi < 4; ++mi) {
        int grb = row0 + wr + mi * 16 + fq * 4;
#pragma unroll
        for (int reg = 0; reg < 4; ++reg) {
            int gr = grb + reg;
            if (gr < M) {
#pragma unroll
                for (int ni = 0; ni < 4; ++ni) {
                    int gc = col0 + wc + ni * 16 + fm;
                    float val = acc[mi][ni][reg] + bv[ni];
                    if (gc < NH) xlb[(size_t)gr * NH + gc] = (__bf16)val;
                    else         xrf[(size_t)gr * NH + gc - NH] = val;
                }
            }
        }
    }
}

// ---------- CSR build ----------
__global__ __launch_bounds__(256) void hist_kernel(
    const int* __restrict__ ei, int* __restrict__ deg)
{
    int e = blockIdx.x * blockDim.x + threadIdx.x;
    if (e >= ETOT) return;
    int d = (e < NEDGES) ? ei[NEDGES + e] : e - NEDGES;
    atomicAdd(&deg[d], 1);
}

__global__ __launch_bounds__(256) void scan_kernel(
    const int* __restrict__ deg, int* __restrict__ rowptr)
{
    __shared__ int partial[256];
    const int t = threadIdx.x;
    const int CH = (NNODES + 255) / 256;
    const int lo = t * CH, hi = min(lo + CH, NNODES);
    int s = 0;
    for (int i = lo; i < hi; i++) s += deg[i];
    partial[t] = s;
    __syncthreads();
    for (int off = 1; off < 256; off <<= 1) {
        int v = (t >= off) ? partial[t - off] : 0;
        __syncthreads();
        partial[t] += v;
        __syncthreads();
    }
    int run = partial[t] - s;
    for (int i = lo; i < hi; i++) { rowptr[i] = run; run += deg[i]; }
    if (t == 255) rowptr[NNODES] = partial[255];
}

__global__ __launch_bounds__(256) void scatter_kernel(
    const int* __restrict__ ei, const int* __restrict__ rowptr,
    int* __restrict__ cursor, int* __restrict__ perm_src)
{
    int e = blockIdx.x * blockDim.x + threadIdx.x;
    if (e >= ETOT) return;
    int s, d;
    if (e < NEDGES) { s = ei[e]; d = ei[NEDGES + e]; }
    else { s = e - NEDGES; d = s; }
    int pos = atomicAdd(&cursor[d], 1);
    perm_src[rowptr[d] + pos] = s;
}

// ---------- fused GATv2 edge phase + bias + LayerNorm + ELU ----------
// One wave per dst node, online softmax. Edge loop is software-pipelined:
// rows prefetched 2 edges ahead, indices 4 ahead (clamped, branch-free).
template<int HC, int H, bool EMIT>
__global__ __launch_bounds__(256) void gat_ln(
    const __bf16* __restrict__ xlb, const float* __restrict__ xrf,
    const float* __restrict__ att, const float* __restrict__ bo,
    const float* __restrict__ gam, const float* __restrict__ bet,
    const int* __restrict__ rowptr, const int* __restrict__ perm_src,
    float* __restrict__ xout, __bf16* __restrict__ ah, __bf16* __restrict__ al)
{
    constexpr int C = HC / H;
    constexpr int P = HC / 64;
    constexpr int GRP = C / P;
    const int lane = threadIdx.x & 63;
    const int wave = threadIdx.x >> 6;
    const int node = blockIdx.x * 4 + wave;
    const int base = lane * P;

    if (EMIT && node >= NNODES) {       // zero GEMM pad rows
        if (node < MPAD) {
            bf16x8 z = {};
            *(bf16x8*)(ah + (size_t)node * HC + base) = z;
            *(bf16x8*)(al + (size_t)node * HC + base) = z;
        }
        return;
    }
    if (node >= NNODES) return;

    float xrv[P], w[P], bov[P], gmv[P], btv[P];
    const float* pr = xrf + (size_t)node * HC + base;
    if constexpr (P == 8) {
        *(float4*)(xrv)     = *(const float4*)(pr);
        *(float4*)(xrv + 4) = *(const float4*)(pr + 4);
        *(float4*)(w)       = *(const float4*)(att + base);
        *(float4*)(w + 4)   = *(const float4*)(att + base + 4);
        *(float4*)(bov)     = *(const float4*)(bo + base);
        *(float4*)(bov + 4) = *(const float4*)(bo + base + 4);
        *(float4*)(gmv)     = *(const float4*)(gam + base);
        *(float4*)(gmv + 4) = *(const float4*)(gam + base + 4);
        *(float4*)(btv)     = *(const float4*)(bet + base);
        *(float4*)(btv + 4) = *(const float4*)(bet + base + 4);
    } else {
        *(float2*)(xrv) = *(const float2*)(pr);
        *(float2*)(w)   = *(const float2*)(att + base);
        *(float2*)(bov) = *(const float2*)(bo + base);
        *(float2*)(gmv) = *(const float2*)(gam + base);
        *(float2*)(btv) = *(const float2*)(bet + base);
    }

    float m = -1e30f, l = 0.f;
    float acc[P];
#pragma unroll
    for (int j = 0; j < P; j++) acc[j] = 0.f;

    const int r0 = rowptr[node], r1 = rowptr[node + 1];

    auto edge_upd = [&](const float (&a)[P]) {
        float part = 0.f;
#pragma unroll
        for (int j = 0; j < P; j++) {
            float v = a[j] + xrv[j];
            v = v > 0.f ? v : v * NEG_SLOPE;
            part += v * w[j];
        }
#pragma unroll
        for (int off = GRP / 2; off > 0; off >>= 1) part += __shfl_xor(part, off);
        float mn = fmaxf(m, part);
        float scale = __expf(m - mn);
        float pe = __expf(part - mn);
        l = l * scale + pe;
#pragma unroll
        for (int j = 0; j < P; j++) acc[j] = acc[j] * scale + pe * a[j];
        m = mn;
    };

    if constexpr (P == 8) {
        // prologue: rows for r0, r0+1 in flight; indices for r0+2, r0+3
        int sA = perm_src[r0];
        int sB = perm_src[min(r0 + 1, r1 - 1)];
        bf16x8 rA = *(const bf16x8*)(xlb + (size_t)sA * HC + base);
        bf16x8 rB = *(const bf16x8*)(xlb + (size_t)sB * HC + base);
        int sC = perm_src[min(r0 + 2, r1 - 1)];
        int sD = perm_src[min(r0 + 3, r1 - 1)];
        int k = r0;
        for (; k + 1 < r1; k += 2) {
            bf16x8 c0 = rA, c1 = rB;
            rA = *(const bf16x8*)(xlb + (size_t)sC * HC + base);
            rB = *(const bf16x8*)(xlb + (size_t)sD * HC + base);
            sC = perm_src[min(k + 4, r1 - 1)];
            sD = perm_src[min(k + 5, r1 - 1)];
            float a0[8], a1[8];
#pragma unroll
            for (int j = 0; j < 8; j++) { a0[j] = (float)c0[j]; a1[j] = (float)c1[j]; }
            edge_upd(a0);
            edge_upd(a1);
        }
        if (k < r1) {
            float a0[8];
#pragma unroll
            for (int j = 0; j < 8; j++) a0[j] = (float)rA[j];
            edge_upd(a0);
        }
    } else {
        int sA = perm_src[r0];
        int sB = perm_src[min(r0 + 1, r1 - 1)];
        bf16x2 rA = *(const bf16x2*)(xlb + (size_t)sA * HC + base);
        bf16x2 rB = *(const bf16x2*)(xlb + (size_t)sB * HC + base);
        int sC = perm_src[min(r0 + 2, r1 - 1)];
        int sD = perm_src[min(r0 + 3, r1 - 1)];
        int k = r0;
        for (; k + 1 < r1; k += 2) {
            bf16x2 c0 = rA, c1 = rB;
            rA = *(const bf16x2*)(xlb + (size_t)sC * HC + base);
            rB = *(const bf16x2*)(xlb + (size_t)sD * HC + base);
            sC = perm_src[min(k + 4, r1 - 1)];
            sD = perm_src[min(k + 5, r1 - 1)];
            float a0[2] = { (float)c0[0], (float)c0[1] };
            float a1[2] = { (float)c1[0], (float)c1[1] };
            edge_upd(a0);
            edge_upd(a1);
        }
        if (k < r1) {
            float a0[2] = { (float)rA[0], (float)rA[1] };
            edge_upd(a0);
        }
    }

    const float inv = 1.f / l;

    // ---- LayerNorm across the wave (all HC channels of this node) ----
    float v[P];
    float s = 0.f;
#pragma unroll
    for (int j = 0; j < P; j++) {
        v[j] = acc[j] * inv + bov[j];
        s += v[j];
    }
#pragma unroll
    for (int off = 1; off < 64; off <<= 1) s += __shfl_xor(s, off);
    const float mu = s / (float)HC;
    float q = 0.f;
#pragma unroll
    for (int j = 0; j < P; j++) { float dd = v[j] - mu; q += dd * dd; }
#pragma unroll
    for (int off = 1; off < 64; off <<= 1) q += __shfl_xor(q, off);
    const float rstd = rsqrtf(q / (float)HC + LN_EPS);

    if constexpr (EMIT) {
        bf16x8 hv, lv;
#pragma unroll
        for (int j = 0; j < P; j++) {
            float y = (v[j] - mu) * rstd * gmv[j] + btv[j];
            y = y > 0.f ? y : expm1f(y);
            __bf16 h, lo2;
            bf16_split(y, h, lo2);
            hv[j] = h; lv[j] = lo2;
        }
        *(bf16x8*)(ah + (size_t)node * HC + base) = hv;
        *(bf16x8*)(al + (size_t)node * HC + base) = lv;
    } else {
        float o[P];
#pragma unroll
        for (int j = 0; j < P; j++) {
            float y = (v[j] - mu) * rstd * gmv[j] + btv[j];
            o[j] = y > 0.f ? y : expm1f(y);
        }
        if constexpr (P == 2) {
            float2 o0 = { o[0], o[1] };
            *(float2*)(xout + (size_t)node * HC + base) = o0;
        } else {
            float4 o0 = { o[0], o[1], o[2], o[3] };
            float4 o1 = { o[4], o[5], o[6], o[7] };
            *(float4*)(xout + (size_t)node * HC + base) = o0;
            *(float4*)(xout + (size_t)node * HC + base + 4) = o1;
        }
    }
}

// ---------- fused mean-pool (segmented, no atomics) + MLP head ----------
__global__ __launch_bounds__(128) void pool_mlp(
    const float* __restrict__ xfin, const int* __restrict__ batch,
    const float* __restrict__ W1, const float* __restrict__ b1,
    const float* __restrict__ W2, const float* __restrict__ b2,
    const float* __restrict__ W3, const float* __restrict__ b3,
    float* __restrict__ out)
{
    __shared__ int bounds[2];
    __shared__ float pool[128], h1[128], h2[64];
    const int g = blockIdx.x, t = threadIdx.x;
    if (t < 2) {
        int target = g + t;
        int lo = 0, hi = NNODES;
        while (lo < hi) { int mid = (lo + hi) >> 1; if (batch[mid] < target) lo = mid + 1; else hi = mid; }
        bounds[t] = lo;
    }
    __syncthreads();
    const int lo = bounds[0], hi = bounds[1];
    float s = 0.f;
#pragma unroll 4
    for (int n = lo; n < hi; n++) s += xfin[(size_t)n * 128 + t];
    pool[t] = s / (float)max(hi - lo, 1);
    __syncthreads();
    float a = b1[t];
    for (int k = 0; k < 128; k++) a += pool[k] * W1[k * 128 + t];
    h1[t] = fmaxf(a, 0.f);
    __syncthreads();
    if (t < 64) {
        float a2 = b2[t];
        for (int k = 0; k < 128; k++) a2 += h1[k] * W2[k * 64 + t];
        h2[t] = fmaxf(a2, 0.f);
    }
    __syncthreads();
    if (t == 0) {
        float a3 = b3[0];
        for (int k = 0; k < 64; k++) a3 += h2[k] * W3[k];
        out[g] = a3;
    }
}

// =====================================================================
extern "C" void kernel_launch(void* const* d_in, const int* in_sizes, int n_in,
                              void* d_out, int out_size, void* d_ws, size_t ws_size,
                              hipStream_t stream)
{
    const float* x     = (const float*)d_in[0];
    const int*   ei    = (const int*)d_in[1];
    const int*   batch = (const int*)d_in[2];

    const float *Wl[3], *bl[3], *Wr[3], *br[3], *att[3], *bo[3], *ga[3], *be[3];
    for (int l = 0; l < 3; l++) {
        int o = 3 + l * 8;
        Wl[l]  = (const float*)d_in[o + 0];
        bl[l]  = (const float*)d_in[o + 1];
        Wr[l]  = (const float*)d_in[o + 2];
        br[l]  = (const float*)d_in[o + 3];
        att[l] = (const float*)d_in[o + 4];
        bo[l]  = (const float*)d_in[o + 5];
        ga[l]  = (const float*)d_in[o + 6];
        be[l]  = (const float*)d_in[o + 7];
    }
    const float* W1 = (const float*)d_in[27];
    const float* b1 = (const float*)d_in[28];
    const float* W2 = (const float*)d_in[29];
    const float* b2 = (const float*)d_in[30];
    const float* W3 = (const float*)d_in[31];
    const float* b3 = (const float*)d_in[32];

    // workspace layout
    char* w = (char*)d_ws;
    size_t off = 0;
    auto alloc = [&](size_t bytes) {
        void* p = w + off;
        off += (bytes + 255) & ~(size_t)255;
        return p;
    };
    __bf16* xlb   = (__bf16*)alloc((size_t)NNODES * 512 * 2);      // xl (bf16) from GEMM
    float*  xrf   = (float*)alloc((size_t)NNODES * 512 * 4);       // xr (fp32) from GEMM
    float*  xfin  = (float*)alloc((size_t)NNODES * 128 * 4);       // final layer fp32
    __bf16* Axh   = (__bf16*)alloc((size_t)MPAD * 800 * 2);        // A hi (reused [MPAD][512] for layers 1/2)
    __bf16* Axl   = (__bf16*)alloc((size_t)MPAD * 800 * 2);
    __bf16* Bh0   = (__bf16*)alloc((size_t)1024 * 800 * 2);
    __bf16* Bh1   = (__bf16*)alloc((size_t)1024 * 512 * 2);
    __bf16* Bh2   = (__bf16*)alloc((size_t)256 * 512 * 2);
    float*  bp0   = (float*)alloc(1024 * 4);
    float*  bp1   = (float*)alloc(1024 * 4);
    float*  bp2   = (float*)alloc(256 * 4);
    int*    deg      = (int*)alloc((size_t)NNODES * 4);
    int*    rowptr   = (int*)alloc((size_t)(NNODES + 1) * 4);
    int*    cursor   = (int*)alloc((size_t)NNODES * 4);
    int*    perm_src = (int*)alloc((size_t)ETOT * 4);
    __bf16* Ah1 = Axh;   // [MPAD][512] for layers 1/2
    __bf16* Al1 = Axl;

    // ---- input conversion + weight packing ----
    convert_x<<<(MPAD * 800 + 255) / 256, 256, 0, stream>>>(x, Axh, Axl);
    pack_w<<<(1024 * 800 + 255) / 256, 256, 0, stream>>>(Wl[0], Wr[0], bl[0], br[0], Bh0, bp0, 771, 800, 512, 1024);
    pack_w<<<(1024 * 512 + 255) / 256, 256, 0, stream>>>(Wl[1], Wr[1], bl[1], br[1], Bh1, bp1, 512, 512, 512, 1024);
    pack_w<<<(256 * 512 + 255) / 256, 256, 0, stream>>>(Wl[2], Wr[2], bl[2], br[2], Bh2, bp2, 512, 512, 128, 256);

    // ---- build CSR by destination ----
    hipMemsetAsync(deg, 0, (size_t)NNODES * 4, stream);
    hipMemsetAsync(cursor, 0, (size_t)NNODES * 4, stream);
    hist_kernel<<<(ETOT + 255) / 256, 256, 0, stream>>>(ei, deg);
    scan_kernel<<<1, 256, 0, stream>>>(deg, rowptr);
    scatter_kernel<<<(ETOT + 255) / 256, 256, 0, stream>>>(ei, rowptr, cursor, perm_src);

    const int fgrid_pad = (MPAD + 3) / 4;     // covers pad rows for bf16 emit
    const int fgrid     = (NNODES + 3) / 4;

    // ---- layer 0: [10000,771] x [771,1024] ----
    gemm_mfma<<<80 * 8, 256, 0, stream>>>(Axh, Axl, Bh0, bp0, xlb, xrf, NNODES, 800, 1024, 3);
    gat_ln<512, 4, true><<<fgrid_pad, 256, 0, stream>>>(
        xlb, xrf, att[0], bo[0], ga[0], be[0], rowptr, perm_src, nullptr, Ah1, Al1);

    // ---- layer 1: [10000,512] x [512,1024] ----
    gemm_mfma<<<80 * 8, 256, 0, stream>>>(Ah1, Al1, Bh1, bp1, xlb, xrf, NNODES, 512, 1024, 3);
    gat_ln<512, 4, true><<<fgrid_pad, 256, 0, stream>>>(
        xlb, xrf, att[1], bo[1], ga[1], be[1], rowptr, perm_src, nullptr, Ah1, Al1);

    // ---- layer 2: [10000,512] x [512,256] ----
    gemm_mfma<<<80 * 2, 256, 0, stream>>>(Ah1, Al1, Bh2, bp2, xlb, xrf, NNODES, 512, 256, 1);
    gat_ln<128, 1, false><<<fgrid, 256, 0, stream>>>(
        xlb, xrf, att[2], bo[2], ga[2], be[2], rowptr, perm_src, xfin, nullptr, nullptr);

    // ---- fused pool + MLP ----
    pool_mlp<<<NGRAPH, 128, 0, stream>>>(xfin, batch, W1, b1, W2, b2, W3, b3, (float*)d_out);
}

// Round 7
// 391.762 us; speedup vs baseline: 15.2325x; 1.0733x over previous
//
#include <hip/hip_runtime.h>
#include <math.h>

#define NNODES 10000
#define MPAD   10240               // 80*128, padded row count for MFMA GEMM
#define NEDGES 160000
#define ETOT   (NEDGES + NNODES)   // 170000, with self loops
#define NGRAPH 64
#define LN_EPS 1e-5f
#define NEG_SLOPE 0.2f

typedef _Float16 f16x8 __attribute__((ext_vector_type(8)));
typedef _Float16 f16x2 __attribute__((ext_vector_type(2)));
typedef float    f32x4 __attribute__((ext_vector_type(4)));

// ---------- convert x [10000][771] fp32 -> A [MPAD][800] fp16 (zero pad) ----------
__global__ __launch_bounds__(256) void convert_x(
    const float* __restrict__ x, _Float16* __restrict__ ah)
{
    int idx = blockIdx.x * blockDim.x + threadIdx.x;
    if (idx >= MPAD * 800) return;
    int r = idx / 800, k = idx - r * 800;
    float v = (r < NNODES && k < 771) ? x[(size_t)r * 771 + k] : 0.f;
    ah[idx] = (_Float16)v;
}

// ---------- pack weights: Wl|Wr [K][NW] -> B [Np][Kp] fp16 transposed ----------
__global__ __launch_bounds__(256) void pack_w(
    const float* __restrict__ Wl, const float* __restrict__ Wr,
    const float* __restrict__ bl, const float* __restrict__ br,
    _Float16* __restrict__ bh, float* __restrict__ biasp,
    int K, int Kp, int NW, int Np)
{
    int idx = blockIdx.x * blockDim.x + threadIdx.x;
    if (idx < Np) biasp[idx] = (idx < NW) ? bl[idx] : br[idx - NW];
    if (idx >= Np * Kp) return;
    int n = idx / Kp, k = idx - n * Kp;
    float v = 0.f;
    if (k < K) v = (n < NW) ? Wl[(size_t)k * NW + n] : Wr[(size_t)k * NW + (n - NW)];
    bh[idx] = (_Float16)v;
}

// ---------- fp16 MFMA GEMM: C[M][N] = A[M][Kp] @ B[Kp][N] + bias ----------
// A [MPAD][Kp] fp16 row-major; B [N][Kp] fp16 (transposed). 128x128 tile,
// 4 waves x 64x64, BK=32, 16x16x32 f16 MFMA, XCD-aware 1-D grid.
// LDS swizzle: chunk (r, kc) stored at (r*4 + (kc ^ ((r>>1)&3)))*16B -> frag
// reads spread over all 8 granule positions (2-way aliasing = free).
// Epilogue: cols < N/2 -> xl fp16; cols >= N/2 -> xr fp32.
__global__ __launch_bounds__(256) void gemm_mfma(
    const _Float16* __restrict__ Ah, const _Float16* __restrict__ Bh,
    const float* __restrict__ bias,
    _Float16* __restrict__ xlh, float* __restrict__ xrf,
    int M, int Kp, int N, int lognbx)
{
    __shared__ __align__(16) _Float16 sAh[128 * 32];
    __shared__ __align__(16) _Float16 sBh[128 * 32];

    const int tid  = threadIdx.x;
    const int lane = tid & 63;
    const int wave = tid >> 6;
    const int L    = blockIdx.x;
    const int xcd  = L & 7;
    const int t    = L >> 3;
    const int bx   = t & ((1 << lognbx) - 1);
    const int by   = xcd + 8 * (t >> lognbx);
    const int row0 = by * 128;
    const int col0 = bx * 128;
    const int wr = (wave >> 1) * 64;
    const int wc = (wave & 1) * 64;
    const int fm = lane & 15;
    const int fq = lane >> 4;

    f32x4 acc[4][4] = {};

    for (int k0 = 0; k0 < Kp; k0 += 32) {
#pragma unroll
        for (int it = 0; it < 2; ++it) {
            int c  = tid + it * 256;             // 0..511 16B chunks per tile
            int r  = c >> 2;
            int kc = (c & 3) ^ ((r >> 1) & 3);   // swizzled global k-chunk
            size_t ga = (size_t)(row0 + r) * Kp + k0 + kc * 8;
            size_t gb = (size_t)(col0 + r) * Kp + k0 + kc * 8;
            __builtin_amdgcn_global_load_lds(
                (const __attribute__((address_space(1))) void*)(Ah + ga),
                (__attribute__((address_space(3))) void*)(sAh + c * 8), 16, 0, 0);
            __builtin_amdgcn_global_load_lds(
                (const __attribute__((address_space(1))) void*)(Bh + gb),
                (__attribute__((address_space(3))) void*)(sBh + c * 8), 16, 0, 0);
        }
        __syncthreads();

        f16x8 fah[4], fbh[4];
#pragma unroll
        for (int mi = 0; mi < 4; ++mi) {
            int m = wr + mi * 16 + fm;
            int off = (m * 4 + (fq ^ ((m >> 1) & 3))) * 8;
            fah[mi] = *(const f16x8*)(sAh + off);
        }
#pragma unroll
        for (int ni = 0; ni < 4; ++ni) {
            int n = wc + ni * 16 + fm;
            int off = (n * 4 + (fq ^ ((n >> 1) & 3))) * 8;
            fbh[ni] = *(const f16x8*)(sBh + off);
        }
#pragma unroll
        for (int mi = 0; mi < 4; ++mi)
#pragma unroll
            for (int ni = 0; ni < 4; ++ni)
                acc[mi][ni] = __builtin_amdgcn_mfma_f32_16x16x32_f16(fah[mi], fbh[ni], acc[mi][ni], 0, 0, 0);
        __syncthreads();
    }

    const int NH = N >> 1;
    float bv[4];
#pragma unroll
    for (int ni = 0; ni < 4; ++ni) bv[ni] = bias[col0 + wc + ni * 16 + fm];
#pragma unroll
    for (int mi = 0; mi < 4; ++mi) {
        int grb = row0 + wr + mi * 16 + fq * 4;
#pragma unroll
        for (int reg = 0; reg < 4; ++reg) {
            int gr = grb + reg;
            if (gr < M) {
#pragma unroll
                for (int ni = 0; ni < 4; ++ni) {
                    int gc = col0 + wc + ni * 16 + fm;
                    float val = acc[mi][ni][reg] + bv[ni];
                    if (gc < NH) xlh[(size_t)gr * NH + gc] = (_Float16)val;
                    else         xrf[(size_t)gr * NH + gc - NH] = val;
                }
            }
        }
    }
}

// ---------- CSR build ----------
__global__ __launch_bounds__(256) void hist_kernel(
    const int* __restrict__ ei, int* __restrict__ deg)
{
    int e = blockIdx.x * blockDim.x + threadIdx.x;
    if (e >= ETOT) return;
    int d = (e < NEDGES) ? ei[NEDGES + e] : e - NEDGES;
    atomicAdd(&deg[d], 1);
}

__global__ __launch_bounds__(256) void scan_kernel(
    const int* __restrict__ deg, int* __restrict__ rowptr)
{
    __shared__ int partial[256];
    const int t = threadIdx.x;
    const int CH = (NNODES + 255) / 256;
    const int lo = t * CH, hi = min(lo + CH, NNODES);
    int s = 0;
    for (int i = lo; i < hi; i++) s += deg[i];
    partial[t] = s;
    __syncthreads();
    for (int off = 1; off < 256; off <<= 1) {
        int v = (t >= off) ? partial[t - off] : 0;
        __syncthreads();
        partial[t] += v;
        __syncthreads();
    }
    int run = partial[t] - s;
    for (int i = lo; i < hi; i++) { rowptr[i] = run; run += deg[i]; }
    if (t == 255) rowptr[NNODES] = partial[255];
}

__global__ __launch_bounds__(256) void scatter_kernel(
    const int* __restrict__ ei, const int* __restrict__ rowptr,
    int* __restrict__ cursor, int* __restrict__ perm_src)
{
    int e = blockIdx.x * blockDim.x + threadIdx.x;
    if (e >= ETOT) return;
    int s, d;
    if (e < NEDGES) { s = ei[e]; d = ei[NEDGES + e]; }
    else { s = e - NEDGES; d = s; }
    int pos = atomicAdd(&cursor[d], 1);
    perm_src[rowptr[d] + pos] = s;
}

// ---------- fused GATv2 edge phase + bias + LayerNorm + ELU ----------
// One wave per dst node, online softmax, software-pipelined edge loop
// (rows prefetched 2 ahead, indices 4 ahead, clamped branch-free).
template<int HC, int H, bool EMIT>
__global__ __launch_bounds__(256) void gat_ln(
    const _Float16* __restrict__ xlh, const float* __restrict__ xrf,
    const float* __restrict__ att, const float* __restrict__ bo,
    const float* __restrict__ gam, const float* __restrict__ bet,
    const int* __restrict__ rowptr, const int* __restrict__ perm_src,
    float* __restrict__ xout, _Float16* __restrict__ ah)
{
    constexpr int C = HC / H;
    constexpr int P = HC / 64;
    constexpr int GRP = C / P;
    const int lane = threadIdx.x & 63;
    const int wave = threadIdx.x >> 6;
    const int node = blockIdx.x * 4 + wave;
    const int base = lane * P;

    if (EMIT && node >= NNODES) {       // zero GEMM pad rows
        if (node < MPAD) {
            f16x8 z = {};
            *(f16x8*)(ah + (size_t)node * HC + base) = z;
        }
        return;
    }
    if (node >= NNODES) return;

    float xrv[P], w[P], bov[P], gmv[P], btv[P];
    const float* pr = xrf + (size_t)node * HC + base;
    if constexpr (P == 8) {
        *(float4*)(xrv)     = *(const float4*)(pr);
        *(float4*)(xrv + 4) = *(const float4*)(pr + 4);
        *(float4*)(w)       = *(const float4*)(att + base);
        *(float4*)(w + 4)   = *(const float4*)(att + base + 4);
        *(float4*)(bov)     = *(const float4*)(bo + base);
        *(float4*)(bov + 4) = *(const float4*)(bo + base + 4);
        *(float4*)(gmv)     = *(const float4*)(gam + base);
        *(float4*)(gmv + 4) = *(const float4*)(gam + base + 4);
        *(float4*)(btv)     = *(const float4*)(bet + base);
        *(float4*)(btv + 4) = *(const float4*)(bet + base + 4);
    } else {
        *(float2*)(xrv) = *(const float2*)(pr);
        *(float2*)(w)   = *(const float2*)(att + base);
        *(float2*)(bov) = *(const float2*)(bo + base);
        *(float2*)(gmv) = *(const float2*)(gam + base);
        *(float2*)(btv) = *(const float2*)(bet + base);
    }

    float m = -1e30f, l = 0.f;
    float acc[P];
#pragma unroll
    for (int j = 0; j < P; j++) acc[j] = 0.f;

    const int r0 = rowptr[node], r1 = rowptr[node + 1];

    auto edge_upd = [&](const float (&a)[P]) {
        float part = 0.f;
#pragma unroll
        for (int j = 0; j < P; j++) {
            float v = a[j] + xrv[j];
            v = v > 0.f ? v : v * NEG_SLOPE;
            part += v * w[j];
        }
#pragma unroll
        for (int off = GRP / 2; off > 0; off >>= 1) part += __shfl_xor(part, off);
        float mn = fmaxf(m, part);
        float scale = __expf(m - mn);
        float pe = __expf(part - mn);
        l = l * scale + pe;
#pragma unroll
        for (int j = 0; j < P; j++) acc[j] = acc[j] * scale + pe * a[j];
        m = mn;
    };

    if constexpr (P == 8) {
        int sA = perm_src[r0];
        int sB = perm_src[min(r0 + 1, r1 - 1)];
        f16x8 rA = *(const f16x8*)(xlh + (size_t)sA * HC + base);
        f16x8 rB = *(const f16x8*)(xlh + (size_t)sB * HC + base);
        int sC = perm_src[min(r0 + 2, r1 - 1)];
        int sD = perm_src[min(r0 + 3, r1 - 1)];
        int k = r0;
        for (; k + 1 < r1; k += 2) {
            f16x8 c0 = rA, c1 = rB;
            rA = *(const f16x8*)(xlh + (size_t)sC * HC + base);
            rB = *(const f16x8*)(xlh + (size_t)sD * HC + base);
            sC = perm_src[min(k + 4, r1 - 1)];
            sD = perm_src[min(k + 5, r1 - 1)];
            float a0[8], a1[8];
#pragma unroll
            for (int j = 0; j < 8; j++) { a0[j] = (float)c0[j]; a1[j] = (float)c1[j]; }
            edge_upd(a0);
            edge_upd(a1);
        }
        if (k < r1) {
            float a0[8];
#pragma unroll
            for (int j = 0; j < 8; j++) a0[j] = (float)rA[j];
            edge_upd(a0);
        }
    } else {
        int sA = perm_src[r0];
        int sB = perm_src[min(r0 + 1, r1 - 1)];
        f16x2 rA = *(const f16x2*)(xlh + (size_t)sA * HC + base);
        f16x2 rB = *(const f16x2*)(xlh + (size_t)sB * HC + base);
        int sC = perm_src[min(r0 + 2, r1 - 1)];
        int sD = perm_src[min(r0 + 3, r1 - 1)];
        int k = r0;
        for (; k + 1 < r1; k += 2) {
            f16x2 c0 = rA, c1 = rB;
            rA = *(const f16x2*)(xlh + (size_t)sC * HC + base);
            rB = *(const f16x2*)(xlh + (size_t)sD * HC + base);
            sC = perm_src[min(k + 4, r1 - 1)];
            sD = perm_src[min(k + 5, r1 - 1)];
            float a0[2] = { (float)c0[0], (float)c0[1] };
            float a1[2] = { (float)c1[0], (float)c1[1] };
            edge_upd(a0);
            edge_upd(a1);
        }
        if (k < r1) {
            float a0[2] = { (float)rA[0], (float)rA[1] };
            edge_upd(a0);
        }
    }

    const float inv = 1.f / l;

    // ---- LayerNorm across the wave (all HC channels of this node) ----
    float v[P];
    float s = 0.f;
#pragma unroll
    for (int j = 0; j < P; j++) {
        v[j] = acc[j] * inv + bov[j];
        s += v[j];
    }
#pragma unroll
    for (int off = 1; off < 64; off <<= 1) s += __shfl_xor(s, off);
    const float mu = s / (float)HC;
    float q = 0.f;
#pragma unroll
    for (int j = 0; j < P; j++) { float dd = v[j] - mu; q += dd * dd; }
#pragma unroll
    for (int off = 1; off < 64; off <<= 1) q += __shfl_xor(q, off);
    const float rstd = rsqrtf(q / (float)HC + LN_EPS);

    if constexpr (EMIT) {
        f16x8 hv;
#pragma unroll
        for (int j = 0; j < P; j++) {
            float y = (v[j] - mu) * rstd * gmv[j] + btv[j];
            y = y > 0.f ? y : expm1f(y);
            hv[j] = (_Float16)y;
        }
        *(f16x8*)(ah + (size_t)node * HC + base) = hv;
    } else {
        float o[P];
#pragma unroll
        for (int j = 0; j < P; j++) {
            float y = (v[j] - mu) * rstd * gmv[j] + btv[j];
            o[j] = y > 0.f ? y : expm1f(y);
        }
        if constexpr (P == 2) {
            float2 o0 = { o[0], o[1] };
            *(float2*)(xout + (size_t)node * HC + base) = o0;
        } else {
            float4 o0 = { o[0], o[1], o[2], o[3] };
            float4 o1 = { o[4], o[5], o[6], o[7] };
            *(float4*)(xout + (size_t)node * HC + base) = o0;
            *(float4*)(xout + (size_t)node * HC + base + 4) = o1;
        }
    }
}

// ---------- fused mean-pool (segmented, no atomics) + MLP head ----------
__global__ __launch_bounds__(128) void pool_mlp(
    const float* __restrict__ xfin, const int* __restrict__ batch,
    const float* __restrict__ W1, const float* __restrict__ b1,
    const float* __restrict__ W2, const float* __restrict__ b2,
    const float* __restrict__ W3, const float* __restrict__ b3,
    float* __restrict__ out)
{
    __shared__ int bounds[2];
    __shared__ float pool[128], h1[128], h2[64];
    const int g = blockIdx.x, t = threadIdx.x;
    if (t < 2) {
        int target = g + t;
        int lo = 0, hi = NNODES;
        while (lo < hi) { int mid = (lo + hi) >> 1; if (batch[mid] < target) lo = mid + 1; else hi = mid; }
        bounds[t] = lo;
    }
    __syncthreads();
    const int lo = bounds[0], hi = bounds[1];
    float s = 0.f;
#pragma unroll 4
    for (int n = lo; n < hi; n++) s += xfin[(size_t)n * 128 + t];
    pool[t] = s / (float)max(hi - lo, 1);
    __syncthreads();
    float a = b1[t];
    for (int k = 0; k < 128; k++) a += pool[k] * W1[k * 128 + t];
    h1[t] = fmaxf(a, 0.f);
    __syncthreads();
    if (t < 64) {
        float a2 = b2[t];
        for (int k = 0; k < 128; k++) a2 += h1[k] * W2[k * 64 + t];
        h2[t] = fmaxf(a2, 0.f);
    }
    __syncthreads();
    if (t == 0) {
        float a3 = b3[0];
        for (int k = 0; k < 64; k++) a3 += h2[k] * W3[k];
        out[g] = a3;
    }
}

// =====================================================================
extern "C" void kernel_launch(void* const* d_in, const int* in_sizes, int n_in,
                              void* d_out, int out_size, void* d_ws, size_t ws_size,
                              hipStream_t stream)
{
    const float* x     = (const float*)d_in[0];
    const int*   ei    = (const int*)d_in[1];
    const int*   batch = (const int*)d_in[2];

    const float *Wl[3], *bl[3], *Wr[3], *br[3], *att[3], *bo[3], *ga[3], *be[3];
    for (int l = 0; l < 3; l++) {
        int o = 3 + l * 8;
        Wl[l]  = (const float*)d_in[o + 0];
        bl[l]  = (const float*)d_in[o + 1];
        Wr[l]  = (const float*)d_in[o + 2];
        br[l]  = (const float*)d_in[o + 3];
        att[l] = (const float*)d_in[o + 4];
        bo[l]  = (const float*)d_in[o + 5];
        ga[l]  = (const float*)d_in[o + 6];
        be[l]  = (const float*)d_in[o + 7];
    }
    const float* W1 = (const float*)d_in[27];
    const float* b1 = (const float*)d_in[28];
    const float* W2 = (const float*)d_in[29];
    const float* b2 = (const float*)d_in[30];
    const float* W3 = (const float*)d_in[31];
    const float* b3 = (const float*)d_in[32];

    // workspace layout
    char* w = (char*)d_ws;
    size_t off = 0;
    auto alloc = [&](size_t bytes) {
        void* p = w + off;
        off += (bytes + 255) & ~(size_t)255;
        return p;
    };
    _Float16* xlh  = (_Float16*)alloc((size_t)NNODES * 512 * 2);   // xl (fp16) from GEMM
    float*    xrf  = (float*)alloc((size_t)NNODES * 512 * 4);      // xr (fp32) from GEMM
    float*    xfin = (float*)alloc((size_t)NNODES * 128 * 4);      // final layer fp32
    _Float16* Axh  = (_Float16*)alloc((size_t)MPAD * 800 * 2);     // A (reused [MPAD][512] for layers 1/2)
    _Float16* Bh0  = (_Float16*)alloc((size_t)1024 * 800 * 2);
    _Float16* Bh1  = (_Float16*)alloc((size_t)1024 * 512 * 2);
    _Float16* Bh2  = (_Float16*)alloc((size_t)256 * 512 * 2);
    float*    bp0  = (float*)alloc(1024 * 4);
    float*    bp1  = (float*)alloc(1024 * 4);
    float*    bp2  = (float*)alloc(256 * 4);
    int*      deg      = (int*)alloc((size_t)NNODES * 4);
    int*      rowptr   = (int*)alloc((size_t)(NNODES + 1) * 4);
    int*      cursor   = (int*)alloc((size_t)NNODES * 4);
    int*      perm_src = (int*)alloc((size_t)ETOT * 4);
    _Float16* Ah1 = Axh;   // [MPAD][512] for layers 1/2

    // ---- input conversion + weight packing ----
    convert_x<<<(MPAD * 800 + 255) / 256, 256, 0, stream>>>(x, Axh);
    pack_w<<<(1024 * 800 + 255) / 256, 256, 0, stream>>>(Wl[0], Wr[0], bl[0], br[0], Bh0, bp0, 771, 800, 512, 1024);
    pack_w<<<(1024 * 512 + 255) / 256, 256, 0, stream>>>(Wl[1], Wr[1], bl[1], br[1], Bh1, bp1, 512, 512, 512, 1024);
    pack_w<<<(256 * 512 + 255) / 256, 256, 0, stream>>>(Wl[2], Wr[2], bl[2], br[2], Bh2, bp2, 512, 512, 128, 256);

    // ---- build CSR by destination ----
    hipMemsetAsync(deg, 0, (size_t)NNODES * 4, stream);
    hipMemsetAsync(cursor, 0, (size_t)NNODES * 4, stream);
    hist_kernel<<<(ETOT + 255) / 256, 256, 0, stream>>>(ei, deg);
    scan_kernel<<<1, 256, 0, stream>>>(deg, rowptr);
    scatter_kernel<<<(ETOT + 255) / 256, 256, 0, stream>>>(ei, rowptr, cursor, perm_src);

    const int fgrid_pad = (MPAD + 3) / 4;     // covers pad rows for fp16 emit
    const int fgrid     = (NNODES + 3) / 4;

    // ---- layer 0: [10000,771] x [771,1024] ----
    gemm_mfma<<<80 * 8, 256, 0, stream>>>(Axh, Bh0, bp0, xlh, xrf, NNODES, 800, 1024, 3);
    gat_ln<512, 4, true><<<fgrid_pad, 256, 0, stream>>>(
        xlh, xrf, att[0], bo[0], ga[0], be[0], rowptr, perm_src, nullptr, Ah1);

    // ---- layer 1: [10000,512] x [512,1024] ----
    gemm_mfma<<<80 * 8, 256, 0, stream>>>(Ah1, Bh1, bp1, xlh, xrf, NNODES, 512, 1024, 3);
    gat_ln<512, 4, true><<<fgrid_pad, 256, 0, stream>>>(
        xlh, xrf, att[1], bo[1], ga[1], be[1], rowptr, perm_src, nullptr, Ah1);

    // ---- layer 2: [10000,512] x [512,256] ----
    gemm_mfma<<<80 * 2, 256, 0, stream>>>(Ah1, Bh2, bp2, xlh, xrf, NNODES, 512, 256, 1);
    gat_ln<128, 1, false><<<fgrid, 256, 0, stream>>>(
        xlh, xrf, att[2], bo[2], ga[2], be[2], rowptr, perm_src, xfin, nullptr);

    // ---- fused pool + MLP ----
    pool_mlp<<<NGRAPH, 128, 0, stream>>>(xfin, batch, W1, b1, W2, b2, W3, b3, (float*)d_out);
}

// Round 8
// 363.629 us; speedup vs baseline: 16.4110x; 1.0774x over previous
//
#include <hip/hip_runtime.h>
#include <math.h>

#define NNODES 10000
#define MPAD   10240               // 80*128, padded row count for MFMA GEMM
#define NEDGES 160000
#define ETOT   (NEDGES + NNODES)   // 170000, with self loops
#define NGRAPH 64
#define LN_EPS 1e-5f
#define NEG_SLOPE 0.2f

typedef _Float16 f16x8 __attribute__((ext_vector_type(8)));
typedef _Float16 f16x2 __attribute__((ext_vector_type(2)));
typedef float    f32x4 __attribute__((ext_vector_type(4)));
typedef unsigned u32x4 __attribute__((ext_vector_type(4)));

__device__ __forceinline__ f16x8 pk_abs8(f16x8 v) {
    u32x4 u; __builtin_memcpy(&u, &v, 16);
    u &= 0x7fff7fffu;
    f16x8 r; __builtin_memcpy(&r, &u, 16);
    return r;
}
__device__ __forceinline__ f16x2 pk_abs2(f16x2 v) {
    unsigned u; __builtin_memcpy(&u, &v, 4);
    u &= 0x7fff7fffu;
    f16x2 r; __builtin_memcpy(&r, &u, 4);
    return r;
}

// ---------- convert x [10000][771] fp32 -> A [MPAD][800] fp16 (zero pad) ----------
__global__ __launch_bounds__(256) void convert_x(
    const float* __restrict__ x, _Float16* __restrict__ ah)
{
    int idx = blockIdx.x * blockDim.x + threadIdx.x;
    if (idx >= MPAD * 800) return;
    int r = idx / 800, k = idx - r * 800;
    float v = (r < NNODES && k < 771) ? x[(size_t)r * 771 + k] : 0.f;
    ah[idx] = (_Float16)v;
}

// ---------- pack weights: Wl|Wr [K][NW] -> B [Np][Kp] fp16 transposed ----------
__global__ __launch_bounds__(256) void pack_w(
    const float* __restrict__ Wl, const float* __restrict__ Wr,
    const float* __restrict__ bl, const float* __restrict__ br,
    _Float16* __restrict__ bh, float* __restrict__ biasp,
    int K, int Kp, int NW, int Np)
{
    int idx = blockIdx.x * blockDim.x + threadIdx.x;
    if (idx < Np) biasp[idx] = (idx < NW) ? bl[idx] : br[idx - NW];
    if (idx >= Np * Kp) return;
    int n = idx / Kp, k = idx - n * Kp;
    float v = 0.f;
    if (k < K) v = (n < NW) ? Wl[(size_t)k * NW + n] : Wr[(size_t)k * NW + (n - NW)];
    bh[idx] = (_Float16)v;
}

// ---------- fp16 MFMA GEMM: C[M][N] = A[M][Kp] @ B[Kp][N] + bias ----------
// 128x128 tile, 4 waves x 64x64, BK=32, 16x16x32 f16 MFMA, XCD-aware 1-D grid,
// 2-way-aliasing LDS swizzle. Epilogue: cols<N/2 -> xl fp16; cols>=N/2 -> xr fp16.
__global__ __launch_bounds__(256) void gemm_mfma(
    const _Float16* __restrict__ Ah, const _Float16* __restrict__ Bh,
    const float* __restrict__ bias,
    _Float16* __restrict__ xlh, _Float16* __restrict__ xrh,
    int M, int Kp, int N, int lognbx)
{
    __shared__ __align__(16) _Float16 sAh[128 * 32];
    __shared__ __align__(16) _Float16 sBh[128 * 32];

    const int tid  = threadIdx.x;
    const int lane = tid & 63;
    const int wave = tid >> 6;
    const int L    = blockIdx.x;
    const int xcd  = L & 7;
    const int t    = L >> 3;
    const int bx   = t & ((1 << lognbx) - 1);
    const int by   = xcd + 8 * (t >> lognbx);
    const int row0 = by * 128;
    const int col0 = bx * 128;
    const int wr = (wave >> 1) * 64;
    const int wc = (wave & 1) * 64;
    const int fm = lane & 15;
    const int fq = lane >> 4;

    f32x4 acc[4][4] = {};

    for (int k0 = 0; k0 < Kp; k0 += 32) {
#pragma unroll
        for (int it = 0; it < 2; ++it) {
            int c  = tid + it * 256;             // 0..511 16B chunks per tile
            int r  = c >> 2;
            int kc = (c & 3) ^ ((r >> 1) & 3);   // swizzled global k-chunk
            size_t ga = (size_t)(row0 + r) * Kp + k0 + kc * 8;
            size_t gb = (size_t)(col0 + r) * Kp + k0 + kc * 8;
            __builtin_amdgcn_global_load_lds(
                (const __attribute__((address_space(1))) void*)(Ah + ga),
                (__attribute__((address_space(3))) void*)(sAh + c * 8), 16, 0, 0);
            __builtin_amdgcn_global_load_lds(
                (const __attribute__((address_space(1))) void*)(Bh + gb),
                (__attribute__((address_space(3))) void*)(sBh + c * 8), 16, 0, 0);
        }
        __syncthreads();

        f16x8 fah[4], fbh[4];
#pragma unroll
        for (int mi = 0; mi < 4; ++mi) {
            int m = wr + mi * 16 + fm;
            int off = (m * 4 + (fq ^ ((m >> 1) & 3))) * 8;
            fah[mi] = *(const f16x8*)(sAh + off);
        }
#pragma unroll
        for (int ni = 0; ni < 4; ++ni) {
            int n = wc + ni * 16 + fm;
            int off = (n * 4 + (fq ^ ((n >> 1) & 3))) * 8;
            fbh[ni] = *(const f16x8*)(sBh + off);
        }
#pragma unroll
        for (int mi = 0; mi < 4; ++mi)
#pragma unroll
            for (int ni = 0; ni < 4; ++ni)
                acc[mi][ni] = __builtin_amdgcn_mfma_f32_16x16x32_f16(fah[mi], fbh[ni], acc[mi][ni], 0, 0, 0);
        __syncthreads();
    }

    const int NH = N >> 1;
    float bv[4];
#pragma unroll
    for (int ni = 0; ni < 4; ++ni) bv[ni] = bias[col0 + wc + ni * 16 + fm];
#pragma unroll
    for (int mi = 0; mi < 4; ++mi) {
        int grb = row0 + wr + mi * 16 + fq * 4;
#pragma unroll
        for (int reg = 0; reg < 4; ++reg) {
            int gr = grb + reg;
            if (gr < M) {
#pragma unroll
                for (int ni = 0; ni < 4; ++ni) {
                    int gc = col0 + wc + ni * 16 + fm;
                    float val = acc[mi][ni][reg] + bv[ni];
                    if (gc < NH) xlh[(size_t)gr * NH + gc] = (_Float16)val;
                    else         xrh[(size_t)gr * NH + gc - NH] = (_Float16)val;
                }
            }
        }
    }
}

// ---------- CSR build ----------
__global__ __launch_bounds__(256) void hist_kernel(
    const int* __restrict__ ei, int* __restrict__ deg)
{
    int e = blockIdx.x * blockDim.x + threadIdx.x;
    if (e >= ETOT) return;
    int d = (e < NEDGES) ? ei[NEDGES + e] : e - NEDGES;
    atomicAdd(&deg[d], 1);
}

__global__ __launch_bounds__(256) void scan_kernel(
    const int* __restrict__ deg, int* __restrict__ rowptr)
{
    __shared__ int partial[256];
    const int t = threadIdx.x;
    const int CH = (NNODES + 255) / 256;
    const int lo = t * CH, hi = min(lo + CH, NNODES);
    int s = 0;
    for (int i = lo; i < hi; i++) s += deg[i];
    partial[t] = s;
    __syncthreads();
    for (int off = 1; off < 256; off <<= 1) {
        int v = (t >= off) ? partial[t - off] : 0;
        __syncthreads();
        partial[t] += v;
        __syncthreads();
    }
    int run = partial[t] - s;
    for (int i = lo; i < hi; i++) { rowptr[i] = run; run += deg[i]; }
    if (t == 255) rowptr[NNODES] = partial[255];
}

__global__ __launch_bounds__(256) void scatter_kernel(
    const int* __restrict__ ei, const int* __restrict__ rowptr,
    int* __restrict__ cursor, int* __restrict__ perm_src)
{
    int e = blockIdx.x * blockDim.x + threadIdx.x;
    if (e >= ETOT) return;
    int s, d;
    if (e < NEDGES) { s = ei[e]; d = ei[NEDGES + e]; }
    else { s = e - NEDGES; d = s; }
    int pos = atomicAdd(&cursor[d], 1);
    perm_src[rowptr[d] + pos] = s;
}

// ---------- fused GATv2 edge phase + bias + LayerNorm + ELU ----------
// One wave per dst node. Packed-fp16 logit math:
//   leaky(v) = 0.6v + 0.4|v|  =>  logit = sum (0.6 att)*v + (0.4 att)*|v|
// No max-subtraction (logits provably < ~5, exp safe in fp32): pe = exp(logit),
// l += pe, acc[j] += pe * xl[j] (fma_mix). Edge loop software-pipelined.
template<int HC, int H, bool EMIT>
__global__ __launch_bounds__(256) void gat_ln(
    const _Float16* __restrict__ xlh, const _Float16* __restrict__ xrh,
    const float* __restrict__ att, const float* __restrict__ bo,
    const float* __restrict__ gam, const float* __restrict__ bet,
    const int* __restrict__ rowptr, const int* __restrict__ perm_src,
    float* __restrict__ xout, _Float16* __restrict__ ah)
{
    constexpr int C = HC / H;
    constexpr int P = HC / 64;
    constexpr int GRP = C / P;
    const int lane = threadIdx.x & 63;
    const int wave = threadIdx.x >> 6;
    const int node = blockIdx.x * 4 + wave;
    const int base = lane * P;

    if (EMIT && node >= NNODES) {       // zero GEMM pad rows
        if (node < MPAD) {
            f16x8 z = {};
            *(f16x8*)(ah + (size_t)node * HC + base) = z;
        }
        return;
    }
    if (node >= NNODES) return;

    float l = 0.f;
    float acc[P];
#pragma unroll
    for (int j = 0; j < P; j++) acc[j] = 0.f;

    const int r0 = rowptr[node], r1 = rowptr[node + 1];

    if constexpr (P == 8) {
        const f16x8 xrp = *(const f16x8*)(xrh + (size_t)node * HC + base);
        f16x8 w06, w04;
        {
            float4 w0 = *(const float4*)(att + base);
            float4 w1 = *(const float4*)(att + base + 4);
            float wa[8] = { w0.x, w0.y, w0.z, w0.w, w1.x, w1.y, w1.z, w1.w };
#pragma unroll
            for (int j = 0; j < 8; j++) {
                w06[j] = (_Float16)(0.6f * wa[j]);
                w04[j] = (_Float16)(0.4f * wa[j]);
            }
        }
        auto edge_upd = [&](const f16x8 c0) {
            f16x8 v = c0 + xrp;                       // pk_add
            f16x8 s = w06 * v + w04 * pk_abs8(v);     // pk_mul/pk_fma + and
            f16x2 h = (__builtin_shufflevector(s, s, 0, 1) + __builtin_shufflevector(s, s, 2, 3))
                    + (__builtin_shufflevector(s, s, 4, 5) + __builtin_shufflevector(s, s, 6, 7));
            float part = (float)h[0] + (float)h[1];
#pragma unroll
            for (int off = GRP / 2; off > 0; off >>= 1) part += __shfl_xor(part, off);
            float pe = __expf(part);
            l += pe;
#pragma unroll
            for (int j = 0; j < 8; j++) acc[j] += pe * (float)c0[j];
        };

        int sA = perm_src[r0];
        int sB = perm_src[min(r0 + 1, r1 - 1)];
        f16x8 rA = *(const f16x8*)(xlh + (size_t)sA * HC + base);
        f16x8 rB = *(const f16x8*)(xlh + (size_t)sB * HC + base);
        int sC = perm_src[min(r0 + 2, r1 - 1)];
        int sD = perm_src[min(r0 + 3, r1 - 1)];
        int k = r0;
        for (; k + 1 < r1; k += 2) {
            f16x8 c0 = rA, c1 = rB;
            rA = *(const f16x8*)(xlh + (size_t)sC * HC + base);
            rB = *(const f16x8*)(xlh + (size_t)sD * HC + base);
            sC = perm_src[min(k + 4, r1 - 1)];
            sD = perm_src[min(k + 5, r1 - 1)];
            edge_upd(c0);
            edge_upd(c1);
        }
        if (k < r1) edge_upd(rA);
    } else {
        const f16x2 xrp = *(const f16x2*)(xrh + (size_t)node * HC + base);
        f16x2 w06, w04;
        {
            float2 w0 = *(const float2*)(att + base);
            w06[0] = (_Float16)(0.6f * w0.x); w06[1] = (_Float16)(0.6f * w0.y);
            w04[0] = (_Float16)(0.4f * w0.x); w04[1] = (_Float16)(0.4f * w0.y);
        }
        auto edge_upd = [&](const f16x2 c0) {
            f16x2 v = c0 + xrp;
            f16x2 s = w06 * v + w04 * pk_abs2(v);
            float part = (float)s[0] + (float)s[1];
#pragma unroll
            for (int off = GRP / 2; off > 0; off >>= 1) part += __shfl_xor(part, off);
            float pe = __expf(part);
            l += pe;
#pragma unroll
            for (int j = 0; j < 2; j++) acc[j] += pe * (float)c0[j];
        };

        int sA = perm_src[r0];
        int sB = perm_src[min(r0 + 1, r1 - 1)];
        f16x2 rA = *(const f16x2*)(xlh + (size_t)sA * HC + base);
        f16x2 rB = *(const f16x2*)(xlh + (size_t)sB * HC + base);
        int sC = perm_src[min(r0 + 2, r1 - 1)];
        int sD = perm_src[min(r0 + 3, r1 - 1)];
        int k = r0;
        for (; k + 1 < r1; k += 2) {
            f16x2 c0 = rA, c1 = rB;
            rA = *(const f16x2*)(xlh + (size_t)sC * HC + base);
            rB = *(const f16x2*)(xlh + (size_t)sD * HC + base);
            sC = perm_src[min(k + 4, r1 - 1)];
            sD = perm_src[min(k + 5, r1 - 1)];
            edge_upd(c0);
            edge_upd(c1);
        }
        if (k < r1) edge_upd(rA);
    }

    const float inv = 1.f / l;

    // ---- LayerNorm across the wave (all HC channels of this node) ----
    float bov[P], gmv[P], btv[P];
    if constexpr (P == 8) {
        *(float4*)(bov)     = *(const float4*)(bo + base);
        *(float4*)(bov + 4) = *(const float4*)(bo + base + 4);
        *(float4*)(gmv)     = *(const float4*)(gam + base);
        *(float4*)(gmv + 4) = *(const float4*)(gam + base + 4);
        *(float4*)(btv)     = *(const float4*)(bet + base);
        *(float4*)(btv + 4) = *(const float4*)(bet + base + 4);
    } else {
        *(float2*)(bov) = *(const float2*)(bo + base);
        *(float2*)(gmv) = *(const float2*)(gam + base);
        *(float2*)(btv) = *(const float2*)(bet + base);
    }

    float v[P];
    float s = 0.f;
#pragma unroll
    for (int j = 0; j < P; j++) {
        v[j] = acc[j] * inv + bov[j];
        s += v[j];
    }
#pragma unroll
    for (int off = 1; off < 64; off <<= 1) s += __shfl_xor(s, off);
    const float mu = s / (float)HC;
    float q = 0.f;
#pragma unroll
    for (int j = 0; j < P; j++) { float dd = v[j] - mu; q += dd * dd; }
#pragma unroll
    for (int off = 1; off < 64; off <<= 1) q += __shfl_xor(q, off);
    const float rstd = rsqrtf(q / (float)HC + LN_EPS);

    if constexpr (EMIT) {
        f16x8 hv;
#pragma unroll
        for (int j = 0; j < P; j++) {
            float y = (v[j] - mu) * rstd * gmv[j] + btv[j];
            y = y > 0.f ? y : expm1f(y);
            hv[j] = (_Float16)y;
        }
        *(f16x8*)(ah + (size_t)node * HC + base) = hv;
    } else {
        float o[P];
#pragma unroll
        for (int j = 0; j < P; j++) {
            float y = (v[j] - mu) * rstd * gmv[j] + btv[j];
            o[j] = y > 0.f ? y : expm1f(y);
        }
        if constexpr (P == 2) {
            float2 o0 = { o[0], o[1] };
            *(float2*)(xout + (size_t)node * HC + base) = o0;
        } else {
            float4 o0 = { o[0], o[1], o[2], o[3] };
            float4 o1 = { o[4], o[5], o[6], o[7] };
            *(float4*)(xout + (size_t)node * HC + base) = o0;
            *(float4*)(xout + (size_t)node * HC + base + 4) = o1;
        }
    }
}

// ---------- fused mean-pool (segmented, no atomics) + MLP head ----------
__global__ __launch_bounds__(128) void pool_mlp(
    const float* __restrict__ xfin, const int* __restrict__ batch,
    const float* __restrict__ W1, const float* __restrict__ b1,
    const float* __restrict__ W2, const float* __restrict__ b2,
    const float* __restrict__ W3, const float* __restrict__ b3,
    float* __restrict__ out)
{
    __shared__ int bounds[2];
    __shared__ float pool[128], h1[128], h2[64];
    const int g = blockIdx.x, t = threadIdx.x;
    if (t < 2) {
        int target = g + t;
        int lo = 0, hi = NNODES;
        while (lo < hi) { int mid = (lo + hi) >> 1; if (batch[mid] < target) lo = mid + 1; else hi = mid; }
        bounds[t] = lo;
    }
    __syncthreads();
    const int lo = bounds[0], hi = bounds[1];
    float s = 0.f;
#pragma unroll 4
    for (int n = lo; n < hi; n++) s += xfin[(size_t)n * 128 + t];
    pool[t] = s / (float)max(hi - lo, 1);
    __syncthreads();
    float a = b1[t];
    for (int k = 0; k < 128; k++) a += pool[k] * W1[k * 128 + t];
    h1[t] = fmaxf(a, 0.f);
    __syncthreads();
    if (t < 64) {
        float a2 = b2[t];
        for (int k = 0; k < 128; k++) a2 += h1[k] * W2[k * 64 + t];
        h2[t] = fmaxf(a2, 0.f);
    }
    __syncthreads();
    if (t == 0) {
        float a3 = b3[0];
        for (int k = 0; k < 64; k++) a3 += h2[k] * W3[k];
        out[g] = a3;
    }
}

// =====================================================================
extern "C" void kernel_launch(void* const* d_in, const int* in_sizes, int n_in,
                              void* d_out, int out_size, void* d_ws, size_t ws_size,
                              hipStream_t stream)
{
    const float* x     = (const float*)d_in[0];
    const int*   ei    = (const int*)d_in[1];
    const int*   batch = (const int*)d_in[2];

    const float *Wl[3], *bl[3], *Wr[3], *br[3], *att[3], *bo[3], *ga[3], *be[3];
    for (int l = 0; l < 3; l++) {
        int o = 3 + l * 8;
        Wl[l]  = (const float*)d_in[o + 0];
        bl[l]  = (const float*)d_in[o + 1];
        Wr[l]  = (const float*)d_in[o + 2];
        br[l]  = (const float*)d_in[o + 3];
        att[l] = (const float*)d_in[o + 4];
        bo[l]  = (const float*)d_in[o + 5];
        ga[l]  = (const float*)d_in[o + 6];
        be[l]  = (const float*)d_in[o + 7];
    }
    const float* W1 = (const float*)d_in[27];
    const float* b1 = (const float*)d_in[28];
    const float* W2 = (const float*)d_in[29];
    const float* b2 = (const float*)d_in[30];
    const float* W3 = (const float*)d_in[31];
    const float* b3 = (const float*)d_in[32];

    // workspace layout
    char* w = (char*)d_ws;
    size_t off = 0;
    auto alloc = [&](size_t bytes) {
        void* p = w + off;
        off += (bytes + 255) & ~(size_t)255;
        return p;
    };
    _Float16* xlh  = (_Float16*)alloc((size_t)NNODES * 512 * 2);   // xl (fp16) from GEMM
    _Float16* xrh  = (_Float16*)alloc((size_t)NNODES * 512 * 2);   // xr (fp16) from GEMM
    float*    xfin = (float*)alloc((size_t)NNODES * 128 * 4);      // final layer fp32
    _Float16* Axh  = (_Float16*)alloc((size_t)MPAD * 800 * 2);     // A (reused [MPAD][512] for layers 1/2)
    _Float16* Bh0  = (_Float16*)alloc((size_t)1024 * 800 * 2);
    _Float16* Bh1  = (_Float16*)alloc((size_t)1024 * 512 * 2);
    _Float16* Bh2  = (_Float16*)alloc((size_t)256 * 512 * 2);
    float*    bp0  = (float*)alloc(1024 * 4);
    float*    bp1  = (float*)alloc(1024 * 4);
    float*    bp2  = (float*)alloc(256 * 4);
    int*      deg      = (int*)alloc((size_t)NNODES * 4);
    int*      rowptr   = (int*)alloc((size_t)(NNODES + 1) * 4);
    int*      cursor   = (int*)alloc((size_t)NNODES * 4);
    int*      perm_src = (int*)alloc((size_t)ETOT * 4);
    _Float16* Ah1 = Axh;   // [MPAD][512] for layers 1/2

    // ---- input conversion + weight packing ----
    convert_x<<<(MPAD * 800 + 255) / 256, 256, 0, stream>>>(x, Axh);
    pack_w<<<(1024 * 800 + 255) / 256, 256, 0, stream>>>(Wl[0], Wr[0], bl[0], br[0], Bh0, bp0, 771, 800, 512, 1024);
    pack_w<<<(1024 * 512 + 255) / 256, 256, 0, stream>>>(Wl[1], Wr[1], bl[1], br[1], Bh1, bp1, 512, 512, 512, 1024);
    pack_w<<<(256 * 512 + 255) / 256, 256, 0, stream>>>(Wl[2], Wr[2], bl[2], br[2], Bh2, bp2, 512, 512, 128, 256);

    // ---- build CSR by destination ----
    hipMemsetAsync(deg, 0, (size_t)NNODES * 4, stream);
    hipMemsetAsync(cursor, 0, (size_t)NNODES * 4, stream);
    hist_kernel<<<(ETOT + 255) / 256, 256, 0, stream>>>(ei, deg);
    scan_kernel<<<1, 256, 0, stream>>>(deg, rowptr);
    scatter_kernel<<<(ETOT + 255) / 256, 256, 0, stream>>>(ei, rowptr, cursor, perm_src);

    const int fgrid_pad = (MPAD + 3) / 4;     // covers pad rows for fp16 emit
    const int fgrid     = (NNODES + 3) / 4;

    // ---- layer 0: [10000,771] x [771,1024] ----
    gemm_mfma<<<80 * 8, 256, 0, stream>>>(Axh, Bh0, bp0, xlh, xrh, NNODES, 800, 1024, 3);
    gat_ln<512, 4, true><<<fgrid_pad, 256, 0, stream>>>(
        xlh, xrh, att[0], bo[0], ga[0], be[0], rowptr, perm_src, nullptr, Ah1);

    // ---- layer 1: [10000,512] x [512,1024] ----
    gemm_mfma<<<80 * 8, 256, 0, stream>>>(Ah1, Bh1, bp1, xlh, xrh, NNODES, 512, 1024, 3);
    gat_ln<512, 4, true><<<fgrid_pad, 256, 0, stream>>>(
        xlh, xrh, att[1], bo[1], ga[1], be[1], rowptr, perm_src, nullptr, Ah1);

    // ---- layer 2: [10000,512] x [512,256] ----
    gemm_mfma<<<80 * 2, 256, 0, stream>>>(Ah1, Bh2, bp2, xlh, xrh, NNODES, 512, 256, 1);
    gat_ln<128, 1, false><<<fgrid, 256, 0, stream>>>(
        xlh, xrh, att[2], bo[2], ga[2], be[2], rowptr, perm_src, xfin, nullptr);

    // ---- fused pool + MLP ----
    pool_mlp<<<NGRAPH, 128, 0, stream>>>(xfin, batch, W1, b1, W2, b2, W3, b3, (float*)d_out);
}